// Round 6
// baseline (2418.102 us; speedup 1.0000x reference)
//
#include <hip/hip_runtime.h>
#include <cstdint>
#include <cstddef>

#define LQ     2048
#define DM     256
#define NKEY   16384
#define NLVL   4
#define LVLN   4096
#define BM     64
#define BN     128
#define KB     32
#define MGRPS  (LQ / BM)
#define NBLK   (LVLN / BN)   // 32 col-blocks per level
#define CLIPMX 3969
#define QB     8

// ---------- branchless sorted-insert into top-4, register-only ----------
// strict: later-inserted equal values lose (valid when idx inserted ascending)
__device__ __forceinline__ void ins4(float v, int ix, float4& tv, int4& ti) {
  bool c0 = v > tv.x, c1 = v > tv.y, c2 = v > tv.z, c3 = v > tv.w;
  tv.w = c2 ? tv.z : (c3 ? v : tv.w);
  ti.w = c2 ? ti.z : (c3 ? ix : ti.w);
  tv.z = c1 ? tv.y : (c2 ? v : tv.z);
  ti.z = c1 ? ti.y : (c2 ? ix : ti.z);
  tv.y = c0 ? tv.x : (c1 ? v : tv.y);
  ti.y = c0 ? ti.x : (c1 ? ix : ti.y);
  tv.x = c0 ? v : tv.x;
  ti.x = c0 ? ix : ti.x;
}

// tie-break: equal value -> smaller index wins (numpy/jax top_k semantics)
__device__ __forceinline__ void ins4_tb(float v, int ix, float4& tv, int4& ti) {
  bool c0 = (v > tv.x) || (v == tv.x && ix < ti.x);
  bool c1 = (v > tv.y) || (v == tv.y && ix < ti.y);
  bool c2 = (v > tv.z) || (v == tv.z && ix < ti.z);
  bool c3 = (v > tv.w) || (v == tv.w && ix < ti.w);
  tv.w = c2 ? tv.z : (c3 ? v : tv.w);
  ti.w = c2 ? ti.z : (c3 ? ix : ti.w);
  tv.z = c1 ? tv.y : (c2 ? v : tv.z);
  ti.z = c1 ? ti.y : (c2 ? ix : ti.z);
  tv.y = c0 ? tv.x : (c1 ? v : tv.y);
  ti.y = c0 ? ti.x : (c1 ? ix : ti.y);
  tv.x = c0 ? v : tv.x;
  ti.x = c0 ? ix : ti.x;
}

#define FMA4(accv, s, bv)                  \
  accv.x = fmaf(s, bv.x, accv.x);          \
  accv.y = fmaf(s, bv.y, accv.y);          \
  accv.z = fmaf(s, bv.z, accv.z);          \
  accv.w = fmaf(s, bv.w, accv.w);

#define GLOAD(ko)                                                          \
    aR0 = *(const float4*)(Aslab + (size_t)(r0)      * DM + (ko) + s0*4);  \
    aR1 = *(const float4*)(Aslab + (size_t)(r0 + 32) * DM + (ko) + s0*4);  \
    bR0 = *(const float4*)(Bt    + (size_t)(r0)      * DM + (ko) + s0*4);  \
    bR1 = *(const float4*)(Bt    + (size_t)(r0 + 32) * DM + (ko) + s0*4);  \
    bR2 = *(const float4*)(Bt    + (size_t)(r0 + 64) * DM + (ko) + s0*4);  \
    bR3 = *(const float4*)(Bt    + (size_t)(r0 + 96) * DM + (ko) + s0*4);

#define LSTORE(nb)                                                                   \
    As[nb][s0*4+0][r0]    = aR0.x; As[nb][s0*4+1][r0]    = aR0.y;                    \
    As[nb][s0*4+2][r0]    = aR0.z; As[nb][s0*4+3][r0]    = aR0.w;                    \
    As[nb][s0*4+0][r0+32] = aR1.x; As[nb][s0*4+1][r0+32] = aR1.y;                    \
    As[nb][s0*4+2][r0+32] = aR1.z; As[nb][s0*4+3][r0+32] = aR1.w;                    \
    Bs[nb][s0*4+0][r0]    = bR0.x; Bs[nb][s0*4+1][r0]    = bR0.y;                    \
    Bs[nb][s0*4+2][r0]    = bR0.z; Bs[nb][s0*4+3][r0]    = bR0.w;                    \
    Bs[nb][s0*4+0][r0+32] = bR1.x; Bs[nb][s0*4+1][r0+32] = bR1.y;                    \
    Bs[nb][s0*4+2][r0+32] = bR1.z; Bs[nb][s0*4+3][r0+32] = bR1.w;                    \
    Bs[nb][s0*4+0][r0+64] = bR2.x; Bs[nb][s0*4+1][r0+64] = bR2.y;                    \
    Bs[nb][s0*4+2][r0+64] = bR2.z; Bs[nb][s0*4+3][r0+64] = bR2.w;                    \
    Bs[nb][s0*4+0][r0+96] = bR3.x; Bs[nb][s0*4+1][r0+96] = bR3.y;                    \
    Bs[nb][s0*4+2][r0+96] = bR3.z; Bs[nb][s0*4+3][r0+96] = bR3.w;

// ---------- kernel A: fp32 GEMM tile + fused per-block top-4 (epilogue-only) ----------
// grid (MGRPS, NBLK) per level. No corr materialization: writes 64 rows x top-4.
// cvL/ciL: [LQ][NBLK][4] for this level.
__global__ __launch_bounds__(256, 2) void gemm_topk(
    const float* __restrict__ Qm, const float* __restrict__ Kb,
    float* __restrict__ cvL, int* __restrict__ ciL)
{
  const int tid  = threadIdx.x;
  const int mgrp = blockIdx.x;
  const int nb2  = blockIdx.y;
  const int ty = tid >> 4, tx = tid & 15;
  const int r0 = tid >> 3, s0 = tid & 7;

  __shared__ __align__(16) float As[2][KB][BM + 4];   // 4352 floats/buf-pair
  __shared__ __align__(16) float Bs[2][KB][BN + 4];   // 8448 floats

  const float* Aslab = Qm + (size_t)mgrp * BM * DM;
  const float* Bt    = Kb + (size_t)nb2 * BN * DM;

  float4 c0l = {0,0,0,0}, c0h = {0,0,0,0};
  float4 c1l = {0,0,0,0}, c1h = {0,0,0,0};
  float4 c2l = {0,0,0,0}, c2h = {0,0,0,0};
  float4 c3l = {0,0,0,0}, c3h = {0,0,0,0};

  float4 aR0, aR1, bR0, bR1, bR2, bR3;

  GLOAD(0)
  LSTORE(0)

#pragma unroll 1
  for (int kc = 0; kc < DM / KB; ++kc) {
    __syncthreads();
    if (kc < DM / KB - 1) {
      GLOAD((kc + 1) * KB)
    }
    const int buf = kc & 1;
#pragma unroll
    for (int k = 0; k < KB; ++k) {
      const float4 av = *(const float4*)&As[buf][k][ty * 4];
      const float4 b0 = *(const float4*)&Bs[buf][k][tx * 4];
      const float4 b1 = *(const float4*)&Bs[buf][k][64 + tx * 4];
      FMA4(c0l, av.x, b0) FMA4(c0h, av.x, b1)
      FMA4(c1l, av.y, b0) FMA4(c1h, av.y, b1)
      FMA4(c2l, av.z, b0) FMA4(c2h, av.z, b1)
      FMA4(c3l, av.w, b0) FMA4(c3h, av.w, b1)
    }
    if (kc < DM / KB - 1) {
      LSTORE((kc & 1) ^ 1)
    }
  }

  // ---- fused epilogue: per-thread strict top-4 per row (indices ascending) ----
  const float4 NEGI = {-3.4e38f, -3.4e38f, -3.4e38f, -3.4e38f};
  const int4   MAXI = {0x7fffffff, 0x7fffffff, 0x7fffffff, 0x7fffffff};
  const int base = nb2 * BN + tx * 4;   // level-local column index
  float4 tv0 = NEGI, tv1 = NEGI, tv2 = NEGI, tv3 = NEGI;
  int4   ti0 = MAXI, ti1 = MAXI, ti2 = MAXI, ti3 = MAXI;

  ins4(c0l.x, base + 0, tv0, ti0); ins4(c0l.y, base + 1, tv0, ti0);
  ins4(c0l.z, base + 2, tv0, ti0); ins4(c0l.w, base + 3, tv0, ti0);
  ins4(c0h.x, base + 64, tv0, ti0); ins4(c0h.y, base + 65, tv0, ti0);
  ins4(c0h.z, base + 66, tv0, ti0); ins4(c0h.w, base + 67, tv0, ti0);

  ins4(c1l.x, base + 0, tv1, ti1); ins4(c1l.y, base + 1, tv1, ti1);
  ins4(c1l.z, base + 2, tv1, ti1); ins4(c1l.w, base + 3, tv1, ti1);
  ins4(c1h.x, base + 64, tv1, ti1); ins4(c1h.y, base + 65, tv1, ti1);
  ins4(c1h.z, base + 66, tv1, ti1); ins4(c1h.w, base + 67, tv1, ti1);

  ins4(c2l.x, base + 0, tv2, ti2); ins4(c2l.y, base + 1, tv2, ti2);
  ins4(c2l.z, base + 2, tv2, ti2); ins4(c2l.w, base + 3, tv2, ti2);
  ins4(c2h.x, base + 64, tv2, ti2); ins4(c2h.y, base + 65, tv2, ti2);
  ins4(c2h.z, base + 66, tv2, ti2); ins4(c2h.w, base + 67, tv2, ti2);

  ins4(c3l.x, base + 0, tv3, ti3); ins4(c3l.y, base + 1, tv3, ti3);
  ins4(c3l.z, base + 2, tv3, ti3); ins4(c3l.w, base + 3, tv3, ti3);
  ins4(c3h.x, base + 64, tv3, ti3); ins4(c3h.y, base + 65, tv3, ti3);
  ins4(c3h.z, base + 66, tv3, ti3); ins4(c3h.w, base + 67, tv3, ti3);

  // ---- LDS merge: 16 per-thread lists -> per-row top-4 (round-1-proven) ----
  __syncthreads();
  float* mv = (float*)(void*)&As[0][0][0];  // 64*16*4 = 4096 floats (<= 4352)
  int*   mi = (int*)(void*)&Bs[0][0][0];    // 4096 ints (<= 8448)
  {
    int o0 = ((ty * 4 + 0) * 16 + tx) * 4;
    mv[o0+0] = tv0.x; mv[o0+1] = tv0.y; mv[o0+2] = tv0.z; mv[o0+3] = tv0.w;
    mi[o0+0] = ti0.x; mi[o0+1] = ti0.y; mi[o0+2] = ti0.z; mi[o0+3] = ti0.w;
    int o1 = ((ty * 4 + 1) * 16 + tx) * 4;
    mv[o1+0] = tv1.x; mv[o1+1] = tv1.y; mv[o1+2] = tv1.z; mv[o1+3] = tv1.w;
    mi[o1+0] = ti1.x; mi[o1+1] = ti1.y; mi[o1+2] = ti1.z; mi[o1+3] = ti1.w;
    int o2 = ((ty * 4 + 2) * 16 + tx) * 4;
    mv[o2+0] = tv2.x; mv[o2+1] = tv2.y; mv[o2+2] = tv2.z; mv[o2+3] = tv2.w;
    mi[o2+0] = ti2.x; mi[o2+1] = ti2.y; mi[o2+2] = ti2.z; mi[o2+3] = ti2.w;
    int o3 = ((ty * 4 + 3) * 16 + tx) * 4;
    mv[o3+0] = tv3.x; mv[o3+1] = tv3.y; mv[o3+2] = tv3.z; mv[o3+3] = tv3.w;
    mi[o3+0] = ti3.x; mi[o3+1] = ti3.y; mi[o3+2] = ti3.z; mi[o3+3] = ti3.w;
  }
  __syncthreads();
  if (tid < BM) {
    float4 bv = NEGI;
    int4   bi = MAXI;
#pragma unroll 1
    for (int c = 0; c < 16; ++c) {
      const int o = (tid * 16 + c) * 4;
      ins4_tb(mv[o+0], mi[o+0], bv, bi);
      ins4_tb(mv[o+1], mi[o+1], bv, bi);
      ins4_tb(mv[o+2], mi[o+2], bv, bi);
      ins4_tb(mv[o+3], mi[o+3], bv, bi);
    }
    const int q = mgrp * BM + tid;
    const size_t o = ((size_t)q * NBLK + nb2) * 4;
    cvL[o+0] = bv.x; cvL[o+1] = bv.y; cvL[o+2] = bv.z; cvL[o+3] = bv.w;
    ciL[o+0] = bi.x; ciL[o+1] = bi.y; ciL[o+2] = bi.z; ciL[o+3] = bi.w;
  }
}

// ---------- kernel B: merge 32 col-blocks -> final top-4, emit tix + sloc ----------
// one thread per (q, level); cv/ci are [NLVL][LQ][NBLK][4]
__global__ __launch_bounds__(256) void merge_topk(
    const float* __restrict__ cv, const int* __restrict__ ci,
    int* __restrict__ tix, float* __restrict__ sloc)
{
  const int g = blockIdx.x * 256 + threadIdx.x;
  if (g >= LQ * NLVL) return;
  const int q = g >> 2, l = g & 3;

  const float4 NEGI = {-3.4e38f, -3.4e38f, -3.4e38f, -3.4e38f};
  const int4   MAXI = {0x7fffffff, 0x7fffffff, 0x7fffffff, 0x7fffffff};
  float4 bv = NEGI;
  int4   bi = MAXI;

  const float* cvp = cv + (((size_t)l * LQ + q) * NBLK) * 4;
  const int*   cip = ci + (((size_t)l * LQ + q) * NBLK) * 4;
#pragma unroll 1
  for (int nb = 0; nb < NBLK; ++nb) {
    const float4 v = *(const float4*)(cvp + nb * 4);
    const int4   x = *(const int4*)(cip + nb * 4);
    ins4_tb(v.x, x.x, bv, bi);
    ins4_tb(v.y, x.y, bv, bi);
    ins4_tb(v.z, x.z, bv, bi);
    ins4_tb(v.w, x.w, bv, bi);
  }

  int bia[4] = {bi.x, bi.y, bi.z, bi.w};
  float* sl = sloc + (size_t)g * 72;   // 36 points * 2
#pragma unroll
  for (int p = 0; p < 4; ++p) {
    const int li = bia[p];             // level-local index [0,4096)
    tix[g * 4 + p] = li;
#pragma unroll
    for (int n9 = 0; n9 < 9; ++n9) {
      const int dy = n9 / 3 - 1, dx = n9 % 3 - 1;
      int r = li + dy * 64 + dx;
      r = r < 0 ? 0 : (r > CLIPMX ? CLIPMX : r);
      sl[(n9 * 4 + p) * 2 + 0] = (float)(r >> 6) * 0.015625f;
      sl[(n9 * 4 + p) * 2 + 1] = (float)(r & 63) * 0.015625f;
    }
  }
}

// ---------- kernel C: gather + accumulate pre-projection output ----------
__global__ void samp_acc(const float* __restrict__ V, const int* __restrict__ tix,
                         float* __restrict__ pre)
{
  const int q = blockIdx.x, d = threadIdx.x;
  const int nei[9] = {-65, -64, -63, -1, 0, 1, 63, 64, 65};
  float acc = 0.f;
#pragma unroll 1
  for (int l = 0; l < NLVL; ++l) {
    const float* Vb = V + (size_t)l * LVLN * DM;
    for (int p = 0; p < 4; ++p) {
      const int p0 = tix[(q * NLVL + l) * 4 + p];
      const int xw = p0 >> 6, yh = p0 & 63;
      if (p0 >= 65 && p0 <= 3904 && yh >= 1 && yh <= 62) {
        // fast path: 4x4 window, weights [1,2,2,1] x [1,2,2,1]
#pragma unroll
        for (int a = 0; a < 4; ++a) {
          const int y = yh - 2 + a;
          if (y < 0) continue;
          const float wa = (a == 1 || a == 2) ? 2.f : 1.f;
#pragma unroll
          for (int bb = 0; bb < 4; ++bb) {
            const int x = xw - 2 + bb;
            if (x < 0) continue;
            const float wb = (bb == 1 || bb == 2) ? 2.f : 1.f;
            acc = fmaf(wa * wb, Vb[(size_t)(y * 64 + x) * DM + d], acc);
          }
        }
      } else {
        // exact per-neighbor path with clip + border masks
#pragma unroll
        for (int n9 = 0; n9 < 9; ++n9) {
          int r = p0 + nei[n9];
          r = r < 0 ? 0 : (r > CLIPMX ? CLIPMX : r);
          const int x = r >> 6, y = r & 63;
          const int b0 = y * 64 + x;
          float s = Vb[(size_t)b0 * DM + d];
          if (x > 0) s += Vb[(size_t)(b0 - 1) * DM + d];
          if (y > 0) {
            s += Vb[(size_t)(b0 - 64) * DM + d];
            if (x > 0) s += Vb[(size_t)(b0 - 65) * DM + d];
          }
          acc += s;
        }
      }
    }
  }
  pre[(size_t)q * DM + d] = acc * (0.25f / 144.f);
}

// ---------- transpose out_w (256x256) ----------
__global__ void transp_w(const float* __restrict__ W, float* __restrict__ Wt)
{
  __shared__ float t[32][33];
  const int bx = blockIdx.x * 32, by = blockIdx.y * 32;
  t[threadIdx.y][threadIdx.x] = W[(size_t)(by + threadIdx.y) * DM + bx + threadIdx.x];
  __syncthreads();
  Wt[(size_t)(bx + threadIdx.y) * DM + by + threadIdx.x] = t[threadIdx.x][threadIdx.y];
}

// ---------- out = pre @ W^T + b ----------
__global__ __launch_bounds__(256) void proj_out(
    const float* __restrict__ pre, const float* __restrict__ Wt,
    const float* __restrict__ bias, float* __restrict__ outp)
{
  const int q0 = blockIdx.x * QB;
  const int e = threadIdx.x;
  float acc[QB];
#pragma unroll
  for (int i = 0; i < QB; ++i) acc[i] = 0.f;
#pragma unroll 4
  for (int d = 0; d < DM; ++d) {
    const float w = Wt[(size_t)d * DM + e];
#pragma unroll
    for (int qq = 0; qq < QB; ++qq)
      acc[qq] = fmaf(pre[(size_t)(q0 + qq) * DM + d], w, acc[qq]);
  }
  const float be = bias[e];
#pragma unroll
  for (int qq = 0; qq < QB; ++qq)
    outp[(size_t)(q0 + qq) * DM + e] = acc[qq] + be;
}

extern "C" void kernel_launch(void* const* d_in, const int* in_sizes, int n_in,
                              void* d_out, int out_size, void* d_ws, size_t ws_size,
                              hipStream_t stream)
{
  const float* Q    = (const float*)d_in[0];   // [2048][256]
  const float* V    = (const float*)d_in[2];   // [16384][256]
  const float* W    = (const float*)d_in[5];   // [256][256]
  const float* bias = (const float*)d_in[6];   // [256]

  float* outp = (float*)d_out;                 // [2048][256]
  float* sloc = outp + (size_t)LQ * DM;        // [2048][4][36][2]

  char* ws = (char*)d_ws;
  const size_t MB = 1 << 20;
  // cand buffers: [NLVL][LQ][NBLK][4] = 1M entries each
  float* cv  = (float*)(ws);                   // 4 MB
  int*   ci  = (int*)  (ws + 4 * MB);          // 4 MB
  int*   tix = (int*)  (ws + 8 * MB);          // 128 KB
  float* pre = (float*)(ws + 8 * MB + 256 * 1024);    // 2 MB
  float* Wt  = (float*)(ws + 10 * MB + 256 * 1024);   // 256 KB

  for (int l = 0; l < NLVL; ++l) {
    gemm_topk<<<dim3(MGRPS, NBLK), 256, 0, stream>>>(
        Q, V + (size_t)l * LVLN * DM,
        cv + (size_t)l * LQ * NBLK * 4,
        ci + (size_t)l * LQ * NBLK * 4);
  }
  merge_topk<<<dim3((LQ * NLVL + 255) / 256), 256, 0, stream>>>(cv, ci, tix, sloc);
  samp_acc<<<dim3(LQ), 256, 0, stream>>>(V, tix, pre);
  transp_w<<<dim3(8, 8), dim3(32, 32), 0, stream>>>(W, Wt);
  proj_out<<<dim3(LQ / QB), 256, 0, stream>>>(pre, Wt, bias, outp);
}

// Round 8
// 1019.981 us; speedup vs baseline: 2.3707x; 2.3707x over previous
//
#include <hip/hip_runtime.h>
#include <cstdint>
#include <cstddef>

#define LQ     2048
#define DM     256
#define NKEY   16384
#define NLVL   4
#define LVLN   4096
#define TBM    128
#define TBN    128
#define TKB    32
#define NBLK   (LVLN / TBN)   // 32 col-blocks per level
#define CLIPMX 3969
#define QB     8

// ---------- branchless sorted-insert into top-4, register-only ----------
// strict: later-inserted equal values lose (valid when idx inserted ascending)
__device__ __forceinline__ void ins4(float v, int ix, float4& tv, int4& ti) {
  bool c0 = v > tv.x, c1 = v > tv.y, c2 = v > tv.z, c3 = v > tv.w;
  tv.w = c2 ? tv.z : (c3 ? v : tv.w);
  ti.w = c2 ? ti.z : (c3 ? ix : ti.w);
  tv.z = c1 ? tv.y : (c2 ? v : tv.z);
  ti.z = c1 ? ti.y : (c2 ? ix : ti.z);
  tv.y = c0 ? tv.x : (c1 ? v : tv.y);
  ti.y = c0 ? ti.x : (c1 ? ix : ti.y);
  tv.x = c0 ? v : tv.x;
  ti.x = c0 ? ix : ti.x;
}

// tie-break: equal value -> smaller index wins (numpy/jax top_k semantics)
__device__ __forceinline__ void ins4_tb(float v, int ix, float4& tv, int4& ti) {
  bool c0 = (v > tv.x) || (v == tv.x && ix < ti.x);
  bool c1 = (v > tv.y) || (v == tv.y && ix < ti.y);
  bool c2 = (v > tv.z) || (v == tv.z && ix < ti.z);
  bool c3 = (v > tv.w) || (v == tv.w && ix < ti.w);
  tv.w = c2 ? tv.z : (c3 ? v : tv.w);
  ti.w = c2 ? ti.z : (c3 ? ix : ti.w);
  tv.z = c1 ? tv.y : (c2 ? v : tv.z);
  ti.z = c1 ? ti.y : (c2 ? ix : ti.z);
  tv.y = c0 ? tv.x : (c1 ? v : tv.y);
  ti.y = c0 ? ti.x : (c1 ? ix : ti.y);
  tv.x = c0 ? v : tv.x;
  ti.x = c0 ? ix : ti.x;
}

#define FMA4(accv, s, bv)                  \
  accv.x = fmaf(s, bv.x, accv.x);          \
  accv.y = fmaf(s, bv.y, accv.y);          \
  accv.z = fmaf(s, bv.z, accv.z);          \
  accv.w = fmaf(s, bv.w, accv.w);

// staging: 1024 16B-chunks per 128x32 tile; thread covers chunks {j*256+tid}
#define G8(ko)                                                               \
  aR0 = *(const float4*)(Aslab + (size_t)(r0)      * DM + (ko) + s0 * 4);   \
  aR1 = *(const float4*)(Aslab + (size_t)(r0 + 32) * DM + (ko) + s0 * 4);   \
  aR2 = *(const float4*)(Aslab + (size_t)(r0 + 64) * DM + (ko) + s0 * 4);   \
  aR3 = *(const float4*)(Aslab + (size_t)(r0 + 96) * DM + (ko) + s0 * 4);   \
  bR0 = *(const float4*)(Bslab + (size_t)(r0)      * DM + (ko) + s0 * 4);   \
  bR1 = *(const float4*)(Bslab + (size_t)(r0 + 32) * DM + (ko) + s0 * 4);   \
  bR2 = *(const float4*)(Bslab + (size_t)(r0 + 64) * DM + (ko) + s0 * 4);   \
  bR3 = *(const float4*)(Bslab + (size_t)(r0 + 96) * DM + (ko) + s0 * 4);

#define L8(nb_)                                                                      \
  As[nb_][s0*4+0][r0]    = aR0.x; As[nb_][s0*4+1][r0]    = aR0.y;                    \
  As[nb_][s0*4+2][r0]    = aR0.z; As[nb_][s0*4+3][r0]    = aR0.w;                    \
  As[nb_][s0*4+0][r0+32] = aR1.x; As[nb_][s0*4+1][r0+32] = aR1.y;                    \
  As[nb_][s0*4+2][r0+32] = aR1.z; As[nb_][s0*4+3][r0+32] = aR1.w;                    \
  As[nb_][s0*4+0][r0+64] = aR2.x; As[nb_][s0*4+1][r0+64] = aR2.y;                    \
  As[nb_][s0*4+2][r0+64] = aR2.z; As[nb_][s0*4+3][r0+64] = aR2.w;                    \
  As[nb_][s0*4+0][r0+96] = aR3.x; As[nb_][s0*4+1][r0+96] = aR3.y;                    \
  As[nb_][s0*4+2][r0+96] = aR3.z; As[nb_][s0*4+3][r0+96] = aR3.w;                    \
  Bs[nb_][s0*4+0][r0]    = bR0.x; Bs[nb_][s0*4+1][r0]    = bR0.y;                    \
  Bs[nb_][s0*4+2][r0]    = bR0.z; Bs[nb_][s0*4+3][r0]    = bR0.w;                    \
  Bs[nb_][s0*4+0][r0+32] = bR1.x; Bs[nb_][s0*4+1][r0+32] = bR1.y;                    \
  Bs[nb_][s0*4+2][r0+32] = bR1.z; Bs[nb_][s0*4+3][r0+32] = bR1.w;                    \
  Bs[nb_][s0*4+0][r0+64] = bR2.x; Bs[nb_][s0*4+1][r0+64] = bR2.y;                    \
  Bs[nb_][s0*4+2][r0+64] = bR2.z; Bs[nb_][s0*4+3][r0+64] = bR2.w;                    \
  Bs[nb_][s0*4+0][r0+96] = bR3.x; Bs[nb_][s0*4+1][r0+96] = bR3.y;                    \
  Bs[nb_][s0*4+2][r0+96] = bR3.z; Bs[nb_][s0*4+3][r0+96] = bR3.w;

// ---------- kernel A: fp32 128x128-tile GEMM (8x8 micro) + fused per-block top-4 ----------
// grid (LQ/128, LVLN/128, NLVL), block 256 = 16x16 threads.
// thread (ty,tx): rows ty*8..+7, cols {tx*4..+3} U {64+tx*4..+3}.
__global__ __launch_bounds__(256, 1) void gemm_topk8(
    const float* __restrict__ Qm, const float* __restrict__ Vm,
    float* __restrict__ cv, int* __restrict__ ci)
{
  const int tid = threadIdx.x;
  const int mb = blockIdx.x, nb = blockIdx.y, l = blockIdx.z;
  const int ty = tid >> 4, tx = tid & 15;
  const int r0 = tid >> 3, s0 = tid & 7;

  __shared__ __align__(16) float As[2][TKB][TBM + 4];   // [2][32][132]
  __shared__ __align__(16) float Bs[2][TKB][TBN + 4];

  const float* Aslab = Qm + (size_t)mb * TBM * DM;
  const float* Bslab = Vm + ((size_t)l * LVLN + (size_t)nb * TBN) * DM;

  float4 acL0 = {0,0,0,0}, acL1 = {0,0,0,0}, acL2 = {0,0,0,0}, acL3 = {0,0,0,0};
  float4 acL4 = {0,0,0,0}, acL5 = {0,0,0,0}, acL6 = {0,0,0,0}, acL7 = {0,0,0,0};
  float4 acH0 = {0,0,0,0}, acH1 = {0,0,0,0}, acH2 = {0,0,0,0}, acH3 = {0,0,0,0};
  float4 acH4 = {0,0,0,0}, acH5 = {0,0,0,0}, acH6 = {0,0,0,0}, acH7 = {0,0,0,0};

  float4 aR0, aR1, aR2, aR3, bR0, bR1, bR2, bR3;

  G8(0)
  L8(0)

#pragma unroll 1
  for (int kt = 0; kt < DM / TKB; ++kt) {
    __syncthreads();
    if (kt < DM / TKB - 1) {
      G8((kt + 1) * TKB)
    }
    const int buf = kt & 1;
#pragma unroll
    for (int k = 0; k < TKB; ++k) {
      const float4 av0 = *(const float4*)&As[buf][k][ty * 8];
      const float4 av1 = *(const float4*)&As[buf][k][ty * 8 + 4];
      const float4 b0  = *(const float4*)&Bs[buf][k][tx * 4];
      const float4 b1  = *(const float4*)&Bs[buf][k][64 + tx * 4];
      FMA4(acL0, av0.x, b0) FMA4(acH0, av0.x, b1)
      FMA4(acL1, av0.y, b0) FMA4(acH1, av0.y, b1)
      FMA4(acL2, av0.z, b0) FMA4(acH2, av0.z, b1)
      FMA4(acL3, av0.w, b0) FMA4(acH3, av0.w, b1)
      FMA4(acL4, av1.x, b0) FMA4(acH4, av1.x, b1)
      FMA4(acL5, av1.y, b0) FMA4(acH5, av1.y, b1)
      FMA4(acL6, av1.z, b0) FMA4(acH6, av1.z, b1)
      FMA4(acL7, av1.w, b0) FMA4(acH7, av1.w, b1)
    }
    if (kt < DM / TKB - 1) {
      L8(buf ^ 1)
    }
  }

  // ---- fused epilogue: per-thread top-4 per row (idx ascending), LDS merge ----
  const float4 NEGI = {-3.4e38f, -3.4e38f, -3.4e38f, -3.4e38f};
  const int4   MAXI = {0x7fffffff, 0x7fffffff, 0x7fffffff, 0x7fffffff};
  const int bl = nb * TBN + tx * 4;     // level-local col of low quad
  __syncthreads();                      // all waves done reading staging LDS
  float* mv = (float*)(void*)&As[0][0][0];  // 128*16*4 = 8192 floats (<= 8448)
  int*   mi = (int*)(void*)&Bs[0][0][0];

#define ROWTOP(i, aL, aH)                                                   \
  {                                                                         \
    float4 tv = NEGI; int4 ti = MAXI;                                       \
    ins4(aL.x, bl + 0, tv, ti);  ins4(aL.y, bl + 1, tv, ti);                \
    ins4(aL.z, bl + 2, tv, ti);  ins4(aL.w, bl + 3, tv, ti);                \
    ins4(aH.x, bl + 64, tv, ti); ins4(aH.y, bl + 65, tv, ti);               \
    ins4(aH.z, bl + 66, tv, ti); ins4(aH.w, bl + 67, tv, ti);               \
    const int o = (((ty * 8 + i) * 16) + tx) * 4;                           \
    mv[o+0] = tv.x; mv[o+1] = tv.y; mv[o+2] = tv.z; mv[o+3] = tv.w;         \
    mi[o+0] = ti.x; mi[o+1] = ti.y; mi[o+2] = ti.z; mi[o+3] = ti.w;         \
  }

  ROWTOP(0, acL0, acH0)
  ROWTOP(1, acL1, acH1)
  ROWTOP(2, acL2, acH2)
  ROWTOP(3, acL3, acH3)
  ROWTOP(4, acL4, acH4)
  ROWTOP(5, acL5, acH5)
  ROWTOP(6, acL6, acH6)
  ROWTOP(7, acL7, acH7)

  __syncthreads();
  if (tid < TBM) {
    float4 bv = NEGI;
    int4   bi = MAXI;
#pragma unroll 1
    for (int c = 0; c < 16; ++c) {
      const int o = (tid * 16 + c) * 4;
      ins4_tb(mv[o+0], mi[o+0], bv, bi);
      ins4_tb(mv[o+1], mi[o+1], bv, bi);
      ins4_tb(mv[o+2], mi[o+2], bv, bi);
      ins4_tb(mv[o+3], mi[o+3], bv, bi);
    }
    const int q = mb * TBM + tid;
    const size_t o = (((size_t)l * LQ + q) * NBLK + nb) * 4;
    cv[o+0] = bv.x; cv[o+1] = bv.y; cv[o+2] = bv.z; cv[o+3] = bv.w;
    ci[o+0] = bi.x; ci[o+1] = bi.y; ci[o+2] = bi.z; ci[o+3] = bi.w;
  }
}

// ---------- kernel B: merge 32 col-blocks -> final top-4, emit tix + sloc ----------
// one thread per (q, level); cv/ci are [NLVL][LQ][NBLK][4]
__global__ __launch_bounds__(256) void merge_topk(
    const float* __restrict__ cv, const int* __restrict__ ci,
    int* __restrict__ tix, float* __restrict__ sloc)
{
  const int g = blockIdx.x * 256 + threadIdx.x;
  if (g >= LQ * NLVL) return;
  const int q = g >> 2, l = g & 3;

  const float4 NEGI = {-3.4e38f, -3.4e38f, -3.4e38f, -3.4e38f};
  const int4   MAXI = {0x7fffffff, 0x7fffffff, 0x7fffffff, 0x7fffffff};
  float4 bv = NEGI;
  int4   bi = MAXI;

  const float* cvp = cv + (((size_t)l * LQ + q) * NBLK) * 4;
  const int*   cip = ci + (((size_t)l * LQ + q) * NBLK) * 4;
#pragma unroll 1
  for (int nb = 0; nb < NBLK; ++nb) {
    const float4 v = *(const float4*)(cvp + nb * 4);
    const int4   x = *(const int4*)(cip + nb * 4);
    ins4_tb(v.x, x.x, bv, bi);
    ins4_tb(v.y, x.y, bv, bi);
    ins4_tb(v.z, x.z, bv, bi);
    ins4_tb(v.w, x.w, bv, bi);
  }

  int bia[4] = {bi.x, bi.y, bi.z, bi.w};
  float* sl = sloc + (size_t)g * 72;   // 36 points * 2
#pragma unroll
  for (int p = 0; p < 4; ++p) {
    const int li = bia[p];             // level-local index [0,4096)
    tix[g * 4 + p] = li;
#pragma unroll
    for (int n9 = 0; n9 < 9; ++n9) {
      const int dy = n9 / 3 - 1, dx = n9 % 3 - 1;
      int r = li + dy * 64 + dx;
      r = r < 0 ? 0 : (r > CLIPMX ? CLIPMX : r);
      sl[(n9 * 4 + p) * 2 + 0] = (float)(r >> 6) * 0.015625f;
      sl[(n9 * 4 + p) * 2 + 1] = (float)(r & 63) * 0.015625f;
    }
  }
}

// ---------- kernel C: gather + accumulate pre-projection output ----------
__global__ void samp_acc(const float* __restrict__ V, const int* __restrict__ tix,
                         float* __restrict__ pre)
{
  const int q = blockIdx.x, d = threadIdx.x;
  const int nei[9] = {-65, -64, -63, -1, 0, 1, 63, 64, 65};
  float acc = 0.f;
#pragma unroll 1
  for (int l = 0; l < NLVL; ++l) {
    const float* Vb = V + (size_t)l * LVLN * DM;
    for (int p = 0; p < 4; ++p) {
      const int p0 = tix[(q * NLVL + l) * 4 + p];
      const int xw = p0 >> 6, yh = p0 & 63;
      if (p0 >= 65 && p0 <= 3904 && yh >= 1 && yh <= 62) {
        // fast path: 4x4 window, weights [1,2,2,1] x [1,2,2,1]
#pragma unroll
        for (int a = 0; a < 4; ++a) {
          const int y = yh - 2 + a;
          if (y < 0) continue;
          const float wa = (a == 1 || a == 2) ? 2.f : 1.f;
#pragma unroll
          for (int bb = 0; bb < 4; ++bb) {
            const int x = xw - 2 + bb;
            if (x < 0) continue;
            const float wb = (bb == 1 || bb == 2) ? 2.f : 1.f;
            acc = fmaf(wa * wb, Vb[(size_t)(y * 64 + x) * DM + d], acc);
          }
        }
      } else {
        // exact per-neighbor path with clip + border masks
#pragma unroll
        for (int n9 = 0; n9 < 9; ++n9) {
          int r = p0 + nei[n9];
          r = r < 0 ? 0 : (r > CLIPMX ? CLIPMX : r);
          const int x = r >> 6, y = r & 63;
          const int b0 = y * 64 + x;
          float s = Vb[(size_t)b0 * DM + d];
          if (x > 0) s += Vb[(size_t)(b0 - 1) * DM + d];
          if (y > 0) {
            s += Vb[(size_t)(b0 - 64) * DM + d];
            if (x > 0) s += Vb[(size_t)(b0 - 65) * DM + d];
          }
          acc += s;
        }
      }
    }
  }
  pre[(size_t)q * DM + d] = acc * (0.25f / 144.f);
}

// ---------- transpose out_w (256x256) ----------
__global__ void transp_w(const float* __restrict__ W, float* __restrict__ Wt)
{
  __shared__ float t[32][33];
  const int bx = blockIdx.x * 32, by = blockIdx.y * 32;
  t[threadIdx.y][threadIdx.x] = W[(size_t)(by + threadIdx.y) * DM + bx + threadIdx.x];
  __syncthreads();
  Wt[(size_t)(bx + threadIdx.y) * DM + by + threadIdx.x] = t[threadIdx.x][threadIdx.y];
}

// ---------- out = pre @ W^T + b ----------
__global__ __launch_bounds__(256) void proj_out(
    const float* __restrict__ pre, const float* __restrict__ Wt,
    const float* __restrict__ bias, float* __restrict__ outp)
{
  const int q0 = blockIdx.x * QB;
  const int e = threadIdx.x;
  float acc[QB];
#pragma unroll
  for (int i = 0; i < QB; ++i) acc[i] = 0.f;
#pragma unroll 4
  for (int d = 0; d < DM; ++d) {
    const float w = Wt[(size_t)d * DM + e];
#pragma unroll
    for (int qq = 0; qq < QB; ++qq)
      acc[qq] = fmaf(pre[(size_t)(q0 + qq) * DM + d], w, acc[qq]);
  }
  const float be = bias[e];
#pragma unroll
  for (int qq = 0; qq < QB; ++qq)
    outp[(size_t)(q0 + qq) * DM + e] = acc[qq] + be;
}

extern "C" void kernel_launch(void* const* d_in, const int* in_sizes, int n_in,
                              void* d_out, int out_size, void* d_ws, size_t ws_size,
                              hipStream_t stream)
{
  const float* Q    = (const float*)d_in[0];   // [2048][256]
  const float* V    = (const float*)d_in[2];   // [16384][256]
  const float* W    = (const float*)d_in[5];   // [256][256]
  const float* bias = (const float*)d_in[6];   // [256]

  float* outp = (float*)d_out;                 // [2048][256]
  float* sloc = outp + (size_t)LQ * DM;        // [2048][4][36][2]

  char* ws = (char*)d_ws;
  const size_t MB = 1 << 20;
  // cand buffers: [NLVL][LQ][NBLK][4] = 1M entries each
  float* cv  = (float*)(ws);                   // 4 MB
  int*   ci  = (int*)  (ws + 4 * MB);          // 4 MB
  int*   tix = (int*)  (ws + 8 * MB);          // 128 KB
  float* pre = (float*)(ws + 8 * MB + 256 * 1024);    // 2 MB
  float* Wt  = (float*)(ws + 10 * MB + 256 * 1024);   // 256 KB

  gemm_topk8<<<dim3(LQ / TBM, LVLN / TBN, NLVL), 256, 0, stream>>>(Q, V, cv, ci);
  merge_topk<<<dim3((LQ * NLVL + 255) / 256), 256, 0, stream>>>(cv, ci, tix, sloc);
  samp_acc<<<dim3(LQ), 256, 0, stream>>>(V, tix, pre);
  transp_w<<<dim3(8, 8), dim3(32, 32), 0, stream>>>(W, Wt);
  proj_out<<<dim3(LQ / QB), 256, 0, stream>>>(pre, Wt, bias, outp);
}

// Round 9
// 774.057 us; speedup vs baseline: 3.1239x; 1.3177x over previous
//
#include <hip/hip_runtime.h>
#include <cstdint>
#include <cstddef>

#define LQ     2048
#define DM     256
#define NKEY   16384
#define NLVL   4
#define LVLN   4096
#define BM     64
#define BN     128
#define KB     32
#define NBLK   (LVLN / BN)   // 32 col-blocks per level
#define CLIPMX 3969
#define QB     8

// ---------- branchless sorted-insert into top-4, register-only ----------
// strict: later-inserted equal values lose (valid when idx inserted ascending)
__device__ __forceinline__ void ins4(float v, int ix, float4& tv, int4& ti) {
  bool c0 = v > tv.x, c1 = v > tv.y, c2 = v > tv.z, c3 = v > tv.w;
  tv.w = c2 ? tv.z : (c3 ? v : tv.w);
  ti.w = c2 ? ti.z : (c3 ? ix : ti.w);
  tv.z = c1 ? tv.y : (c2 ? v : tv.z);
  ti.z = c1 ? ti.y : (c2 ? ix : ti.z);
  tv.y = c0 ? tv.x : (c1 ? v : tv.y);
  ti.y = c0 ? ti.x : (c1 ? ix : ti.y);
  tv.x = c0 ? v : tv.x;
  ti.x = c0 ? ix : ti.x;
}

// tie-break: equal value -> smaller index wins (numpy/jax top_k semantics)
__device__ __forceinline__ void ins4_tb(float v, int ix, float4& tv, int4& ti) {
  bool c0 = (v > tv.x) || (v == tv.x && ix < ti.x);
  bool c1 = (v > tv.y) || (v == tv.y && ix < ti.y);
  bool c2 = (v > tv.z) || (v == tv.z && ix < ti.z);
  bool c3 = (v > tv.w) || (v == tv.w && ix < ti.w);
  tv.w = c2 ? tv.z : (c3 ? v : tv.w);
  ti.w = c2 ? ti.z : (c3 ? ix : ti.w);
  tv.z = c1 ? tv.y : (c2 ? v : tv.z);
  ti.z = c1 ? ti.y : (c2 ? ix : ti.z);
  tv.y = c0 ? tv.x : (c1 ? v : tv.y);
  ti.y = c0 ? ti.x : (c1 ? ix : ti.y);
  tv.x = c0 ? v : tv.x;
  ti.x = c0 ? ix : ti.x;
}

#define FMA4(accv, s, bv)                  \
  accv.x = fmaf(s, bv.x, accv.x);          \
  accv.y = fmaf(s, bv.y, accv.y);          \
  accv.z = fmaf(s, bv.z, accv.z);          \
  accv.w = fmaf(s, bv.w, accv.w);

#define GLOAD(ko)                                                          \
    aR0 = *(const float4*)(Aslab + (size_t)(r0)      * DM + (ko) + s0*4);  \
    aR1 = *(const float4*)(Aslab + (size_t)(r0 + 32) * DM + (ko) + s0*4);  \
    bR0 = *(const float4*)(Bslab + (size_t)(r0)      * DM + (ko) + s0*4);  \
    bR1 = *(const float4*)(Bslab + (size_t)(r0 + 32) * DM + (ko) + s0*4);  \
    bR2 = *(const float4*)(Bslab + (size_t)(r0 + 64) * DM + (ko) + s0*4);  \
    bR3 = *(const float4*)(Bslab + (size_t)(r0 + 96) * DM + (ko) + s0*4);

#define LSTORE(nb_)                                                                  \
    As[nb_][s0*4+0][r0]    = aR0.x; As[nb_][s0*4+1][r0]    = aR0.y;                  \
    As[nb_][s0*4+2][r0]    = aR0.z; As[nb_][s0*4+3][r0]    = aR0.w;                  \
    As[nb_][s0*4+0][r0+32] = aR1.x; As[nb_][s0*4+1][r0+32] = aR1.y;                  \
    As[nb_][s0*4+2][r0+32] = aR1.z; As[nb_][s0*4+3][r0+32] = aR1.w;                  \
    Bs[nb_][s0*4+0][r0]    = bR0.x; Bs[nb_][s0*4+1][r0]    = bR0.y;                  \
    Bs[nb_][s0*4+2][r0]    = bR0.z; Bs[nb_][s0*4+3][r0]    = bR0.w;                  \
    Bs[nb_][s0*4+0][r0+32] = bR1.x; Bs[nb_][s0*4+1][r0+32] = bR1.y;                  \
    Bs[nb_][s0*4+2][r0+32] = bR1.z; Bs[nb_][s0*4+3][r0+32] = bR1.w;                  \
    Bs[nb_][s0*4+0][r0+64] = bR2.x; Bs[nb_][s0*4+1][r0+64] = bR2.y;                  \
    Bs[nb_][s0*4+2][r0+64] = bR2.z; Bs[nb_][s0*4+3][r0+64] = bR2.w;                  \
    Bs[nb_][s0*4+0][r0+96] = bR3.x; Bs[nb_][s0*4+1][r0+96] = bR3.y;                  \
    Bs[nb_][s0*4+2][r0+96] = bR3.z; Bs[nb_][s0*4+3][r0+96] = bR3.w;

// ---------- kernel A: round-3 GEMM (64x128, 4x8 micro) + fused epilogue top-4 ----------
// grid (LQ/64, NBLK, NLVL), block 256 = 16x16. (256,1): proven 232 VGPR, no spill.
__global__ __launch_bounds__(256, 1) void gemm_topk_z(
    const float* __restrict__ Qm, const float* __restrict__ Vm,
    float* __restrict__ cv, int* __restrict__ ci)
{
  const int tid  = threadIdx.x;
  const int mgrp = blockIdx.x;
  const int nb2  = blockIdx.y;
  const int l    = blockIdx.z;
  const int ty = tid >> 4, tx = tid & 15;
  const int r0 = tid >> 3, s0 = tid & 7;

  __shared__ __align__(16) float As[2][KB][BM + 4];   // 2*32*68*4  = 17.4 KB
  __shared__ __align__(16) float Bs[2][KB][BN + 4];   // 2*32*132*4 = 33.8 KB

  const float* Aslab = Qm + (size_t)mgrp * BM * DM;
  const float* Bslab = Vm + ((size_t)l * LVLN + (size_t)nb2 * BN) * DM;

  float4 c0l = {0,0,0,0}, c0h = {0,0,0,0};
  float4 c1l = {0,0,0,0}, c1h = {0,0,0,0};
  float4 c2l = {0,0,0,0}, c2h = {0,0,0,0};
  float4 c3l = {0,0,0,0}, c3h = {0,0,0,0};

  float4 aR0, aR1, bR0, bR1, bR2, bR3;

  GLOAD(0)
  LSTORE(0)

#pragma unroll 1
  for (int kc = 0; kc < DM / KB; ++kc) {
    __syncthreads();
    if (kc < DM / KB - 1) {
      GLOAD((kc + 1) * KB)
    }
    const int buf = kc & 1;
#pragma unroll
    for (int k = 0; k < KB; ++k) {
      const float4 av = *(const float4*)&As[buf][k][ty * 4];
      const float4 b0 = *(const float4*)&Bs[buf][k][tx * 4];
      const float4 b1 = *(const float4*)&Bs[buf][k][64 + tx * 4];
      FMA4(c0l, av.x, b0) FMA4(c0h, av.x, b1)
      FMA4(c1l, av.y, b0) FMA4(c1h, av.y, b1)
      FMA4(c2l, av.z, b0) FMA4(c2h, av.z, b1)
      FMA4(c3l, av.w, b0) FMA4(c3h, av.w, b1)
    }
    if (kc < DM / KB - 1) {
      LSTORE((kc & 1) ^ 1)
    }
  }

  // ---- fused epilogue: per-row top-4 (local tv/ti, stored immediately) ----
  const float4 NEGI = {-3.4e38f, -3.4e38f, -3.4e38f, -3.4e38f};
  const int4   MAXI = {0x7fffffff, 0x7fffffff, 0x7fffffff, 0x7fffffff};
  const int bl = nb2 * BN + tx * 4;       // level-local col of low quad
  __syncthreads();                        // all waves done with staging LDS
  float* mv = (float*)(void*)&As[0][0][0];  // 64*16*4 = 4096 floats <= 4352
  int*   mi = (int*)(void*)&Bs[0][0][0];    // <= 8448

#define ROWTOP(i, aL, aH)                                                   \
  {                                                                         \
    float4 tv = NEGI; int4 ti = MAXI;                                       \
    ins4(aL.x, bl + 0, tv, ti);  ins4(aL.y, bl + 1, tv, ti);                \
    ins4(aL.z, bl + 2, tv, ti);  ins4(aL.w, bl + 3, tv, ti);                \
    ins4(aH.x, bl + 64, tv, ti); ins4(aH.y, bl + 65, tv, ti);               \
    ins4(aH.z, bl + 66, tv, ti); ins4(aH.w, bl + 67, tv, ti);               \
    const int o = (((ty * 4 + i) * 16) + tx) * 4;                           \
    mv[o+0] = tv.x; mv[o+1] = tv.y; mv[o+2] = tv.z; mv[o+3] = tv.w;         \
    mi[o+0] = ti.x; mi[o+1] = ti.y; mi[o+2] = ti.z; mi[o+3] = ti.w;         \
  }

  ROWTOP(0, c0l, c0h)
  ROWTOP(1, c1l, c1h)
  ROWTOP(2, c2l, c2h)
  ROWTOP(3, c3l, c3h)
#undef ROWTOP

  __syncthreads();
  if (tid < BM) {
    float4 bv = NEGI;
    int4   bi = MAXI;
#pragma unroll 1
    for (int c = 0; c < 16; ++c) {
      const int o = (tid * 16 + c) * 4;
      ins4_tb(mv[o+0], mi[o+0], bv, bi);
      ins4_tb(mv[o+1], mi[o+1], bv, bi);
      ins4_tb(mv[o+2], mi[o+2], bv, bi);
      ins4_tb(mv[o+3], mi[o+3], bv, bi);
    }
    const int q = mgrp * BM + tid;
    const size_t o = (((size_t)l * LQ + q) * NBLK + nb2) * 4;
    cv[o+0] = bv.x; cv[o+1] = bv.y; cv[o+2] = bv.z; cv[o+3] = bv.w;
    ci[o+0] = bi.x; ci[o+1] = bi.y; ci[o+2] = bi.z; ci[o+3] = bi.w;
  }
}

// ---------- kernel B: merge 32 col-blocks -> final top-4, emit tix + sloc ----------
// one thread per (q, level); cv/ci are [NLVL][LQ][NBLK][4]
__global__ __launch_bounds__(256) void merge_topk(
    const float* __restrict__ cv, const int* __restrict__ ci,
    int* __restrict__ tix, float* __restrict__ sloc)
{
  const int g = blockIdx.x * 256 + threadIdx.x;
  if (g >= LQ * NLVL) return;
  const int q = g >> 2, l = g & 3;

  const float4 NEGI = {-3.4e38f, -3.4e38f, -3.4e38f, -3.4e38f};
  const int4   MAXI = {0x7fffffff, 0x7fffffff, 0x7fffffff, 0x7fffffff};
  float4 bv = NEGI;
  int4   bi = MAXI;

  const float* cvp = cv + (((size_t)l * LQ + q) * NBLK) * 4;
  const int*   cip = ci + (((size_t)l * LQ + q) * NBLK) * 4;
#pragma unroll 1
  for (int nb = 0; nb < NBLK; ++nb) {
    const float4 v = *(const float4*)(cvp + nb * 4);
    const int4   x = *(const int4*)(cip + nb * 4);
    ins4_tb(v.x, x.x, bv, bi);
    ins4_tb(v.y, x.y, bv, bi);
    ins4_tb(v.z, x.z, bv, bi);
    ins4_tb(v.w, x.w, bv, bi);
  }

  int bia[4] = {bi.x, bi.y, bi.z, bi.w};
  float* sl = sloc + (size_t)g * 72;   // 36 points * 2
#pragma unroll
  for (int p = 0; p < 4; ++p) {
    const int li = bia[p];             // level-local index [0,4096)
    tix[g * 4 + p] = li;
#pragma unroll
    for (int n9 = 0; n9 < 9; ++n9) {
      const int dy = n9 / 3 - 1, dx = n9 % 3 - 1;
      int r = li + dy * 64 + dx;
      r = r < 0 ? 0 : (r > CLIPMX ? CLIPMX : r);
      sl[(n9 * 4 + p) * 2 + 0] = (float)(r >> 6) * 0.015625f;
      sl[(n9 * 4 + p) * 2 + 1] = (float)(r & 63) * 0.015625f;
    }
  }
}

// ---------- kernel C: gather + accumulate pre-projection output ----------
__global__ void samp_acc(const float* __restrict__ V, const int* __restrict__ tix,
                         float* __restrict__ pre)
{
  const int q = blockIdx.x, d = threadIdx.x;
  const int nei[9] = {-65, -64, -63, -1, 0, 1, 63, 64, 65};
  float acc = 0.f;
#pragma unroll 1
  for (int l = 0; l < NLVL; ++l) {
    const float* Vb = V + (size_t)l * LVLN * DM;
    for (int p = 0; p < 4; ++p) {
      const int p0 = tix[(q * NLVL + l) * 4 + p];
      const int xw = p0 >> 6, yh = p0 & 63;
      if (p0 >= 65 && p0 <= 3904 && yh >= 1 && yh <= 62) {
        // fast path: 4x4 window, weights [1,2,2,1] x [1,2,2,1]
#pragma unroll
        for (int a = 0; a < 4; ++a) {
          const int y = yh - 2 + a;
          if (y < 0) continue;
          const float wa = (a == 1 || a == 2) ? 2.f : 1.f;
#pragma unroll
          for (int bb = 0; bb < 4; ++bb) {
            const int x = xw - 2 + bb;
            if (x < 0) continue;
            const float wb = (bb == 1 || bb == 2) ? 2.f : 1.f;
            acc = fmaf(wa * wb, Vb[(size_t)(y * 64 + x) * DM + d], acc);
          }
        }
      } else {
        // exact per-neighbor path with clip + border masks
#pragma unroll
        for (int n9 = 0; n9 < 9; ++n9) {
          int r = p0 + nei[n9];
          r = r < 0 ? 0 : (r > CLIPMX ? CLIPMX : r);
          const int x = r >> 6, y = r & 63;
          const int b0 = y * 64 + x;
          float s = Vb[(size_t)b0 * DM + d];
          if (x > 0) s += Vb[(size_t)(b0 - 1) * DM + d];
          if (y > 0) {
            s += Vb[(size_t)(b0 - 64) * DM + d];
            if (x > 0) s += Vb[(size_t)(b0 - 65) * DM + d];
          }
          acc += s;
        }
      }
    }
  }
  pre[(size_t)q * DM + d] = acc * (0.25f / 144.f);
}

// ---------- kernel D0: transpose out_w (256x256) ----------
__global__ void transp_w(const float* __restrict__ W, float* __restrict__ Wt)
{
  __shared__ float t[32][33];
  const int bx = blockIdx.x * 32, by = blockIdx.y * 32;
  t[threadIdx.y][threadIdx.x] = W[(size_t)(by + threadIdx.y) * DM + bx + threadIdx.x];
  __syncthreads();
  Wt[(size_t)(bx + threadIdx.y) * DM + by + threadIdx.x] = t[threadIdx.x][threadIdx.y];
}

// ---------- kernel D: out = pre @ W^T + b ----------
__global__ __launch_bounds__(256) void proj_out(
    const float* __restrict__ pre, const float* __restrict__ Wt,
    const float* __restrict__ bias, float* __restrict__ outp)
{
  const int q0 = blockIdx.x * QB;
  const int e = threadIdx.x;
  float acc[QB];
#pragma unroll
  for (int i = 0; i < QB; ++i) acc[i] = 0.f;
#pragma unroll 4
  for (int d = 0; d < DM; ++d) {
    const float w = Wt[(size_t)d * DM + e];
#pragma unroll
    for (int qq = 0; qq < QB; ++qq)
      acc[qq] = fmaf(pre[(size_t)(q0 + qq) * DM + d], w, acc[qq]);
  }
  const float be = bias[e];
#pragma unroll
  for (int qq = 0; qq < QB; ++qq)
    outp[(size_t)(q0 + qq) * DM + e] = acc[qq] + be;
}

extern "C" void kernel_launch(void* const* d_in, const int* in_sizes, int n_in,
                              void* d_out, int out_size, void* d_ws, size_t ws_size,
                              hipStream_t stream)
{
  const float* Q    = (const float*)d_in[0];   // [2048][256]
  const float* V    = (const float*)d_in[2];   // [16384][256]
  const float* W    = (const float*)d_in[5];   // [256][256]
  const float* bias = (const float*)d_in[6];   // [256]

  float* outp = (float*)d_out;                 // [2048][256]
  float* sloc = outp + (size_t)LQ * DM;        // [2048][4][36][2]

  char* ws = (char*)d_ws;
  const size_t MB = 1 << 20;
  // cand buffers: [NLVL][LQ][NBLK][4] = 1M entries each
  float* cv  = (float*)(ws);                   // 4 MB
  int*   ci  = (int*)  (ws + 4 * MB);          // 4 MB
  int*   tix = (int*)  (ws + 8 * MB);          // 128 KB
  float* pre = (float*)(ws + 8 * MB + 256 * 1024);    // 2 MB
  float* Wt  = (float*)(ws + 10 * MB + 256 * 1024);   // 256 KB

  gemm_topk_z<<<dim3(LQ / BM, NBLK, NLVL), 256, 0, stream>>>(Q, V, cv, ci);
  merge_topk<<<dim3((LQ * NLVL + 255) / 256), 256, 0, stream>>>(cv, ci, tix, sloc);
  samp_acc<<<dim3(LQ), 256, 0, stream>>>(V, tix, pre);
  transp_w<<<dim3(8, 8), dim3(32, 32), 0, stream>>>(W, Wt);
  proj_out<<<dim3(LQ / QB), 256, 0, stream>>>(pre, Wt, bias, outp);
}

// Round 10
// 736.165 us; speedup vs baseline: 3.2847x; 1.0515x over previous
//
#include <hip/hip_runtime.h>
#include <cstdint>
#include <cstddef>

#define LQ     2048
#define DM     256
#define NKEY   16384
#define NLVL   4
#define LVLN   4096
#define BM     64
#define BN     128
#define KB     32
#define NBLK   (LVLN / BN)   // 32 col-blocks per level
#define CLIPMX 3969
#define QB     8

// ---------- branchless sorted-insert into top-4, register-only ----------
// strict: later-inserted equal values lose (valid when idx inserted ascending)
__device__ __forceinline__ void ins4(float v, int ix, float4& tv, int4& ti) {
  bool c0 = v > tv.x, c1 = v > tv.y, c2 = v > tv.z, c3 = v > tv.w;
  tv.w = c2 ? tv.z : (c3 ? v : tv.w);
  ti.w = c2 ? ti.z : (c3 ? ix : ti.w);
  tv.z = c1 ? tv.y : (c2 ? v : tv.z);
  ti.z = c1 ? ti.y : (c2 ? ix : ti.z);
  tv.y = c0 ? tv.x : (c1 ? v : tv.y);
  ti.y = c0 ? ti.x : (c1 ? ix : ti.y);
  tv.x = c0 ? v : tv.x;
  ti.x = c0 ? ix : ti.x;
}

// tie-break: equal value -> smaller index wins (numpy/jax top_k semantics)
__device__ __forceinline__ void ins4_tb(float v, int ix, float4& tv, int4& ti) {
  bool c0 = (v > tv.x) || (v == tv.x && ix < ti.x);
  bool c1 = (v > tv.y) || (v == tv.y && ix < ti.y);
  bool c2 = (v > tv.z) || (v == tv.z && ix < ti.z);
  bool c3 = (v > tv.w) || (v == tv.w && ix < ti.w);
  tv.w = c2 ? tv.z : (c3 ? v : tv.w);
  ti.w = c2 ? ti.z : (c3 ? ix : ti.w);
  tv.z = c1 ? tv.y : (c2 ? v : tv.z);
  ti.z = c1 ? ti.y : (c2 ? ix : ti.z);
  tv.y = c0 ? tv.x : (c1 ? v : tv.y);
  ti.y = c0 ? ti.x : (c1 ? ix : ti.y);
  tv.x = c0 ? v : tv.x;
  ti.x = c0 ? ix : ti.x;
}

#define FMA4(accv, s, bv)                  \
  accv.x = fmaf(s, bv.x, accv.x);          \
  accv.y = fmaf(s, bv.y, accv.y);          \
  accv.z = fmaf(s, bv.z, accv.z);          \
  accv.w = fmaf(s, bv.w, accv.w);

#define GLOAD(ko)                                                          \
    aR0 = *(const float4*)(Aslab + (size_t)(r0)      * DM + (ko) + s0*4);  \
    aR1 = *(const float4*)(Aslab + (size_t)(r0 + 32) * DM + (ko) + s0*4);  \
    bR0 = *(const float4*)(Bslab + (size_t)(r0)      * DM + (ko) + s0*4);  \
    bR1 = *(const float4*)(Bslab + (size_t)(r0 + 32) * DM + (ko) + s0*4);  \
    bR2 = *(const float4*)(Bslab + (size_t)(r0 + 64) * DM + (ko) + s0*4);  \
    bR3 = *(const float4*)(Bslab + (size_t)(r0 + 96) * DM + (ko) + s0*4);

#define LSTORE(nb_)                                                                  \
    As[nb_][s0*4+0][r0]    = aR0.x; As[nb_][s0*4+1][r0]    = aR0.y;                  \
    As[nb_][s0*4+2][r0]    = aR0.z; As[nb_][s0*4+3][r0]    = aR0.w;                  \
    As[nb_][s0*4+0][r0+32] = aR1.x; As[nb_][s0*4+1][r0+32] = aR1.y;                  \
    As[nb_][s0*4+2][r0+32] = aR1.z; As[nb_][s0*4+3][r0+32] = aR1.w;                  \
    Bs[nb_][s0*4+0][r0]    = bR0.x; Bs[nb_][s0*4+1][r0]    = bR0.y;                  \
    Bs[nb_][s0*4+2][r0]    = bR0.z; Bs[nb_][s0*4+3][r0]    = bR0.w;                  \
    Bs[nb_][s0*4+0][r0+32] = bR1.x; Bs[nb_][s0*4+1][r0+32] = bR1.y;                  \
    Bs[nb_][s0*4+2][r0+32] = bR1.z; Bs[nb_][s0*4+3][r0+32] = bR1.w;                  \
    Bs[nb_][s0*4+0][r0+64] = bR2.x; Bs[nb_][s0*4+1][r0+64] = bR2.y;                  \
    Bs[nb_][s0*4+2][r0+64] = bR2.z; Bs[nb_][s0*4+3][r0+64] = bR2.w;                  \
    Bs[nb_][s0*4+0][r0+96] = bR3.x; Bs[nb_][s0*4+1][r0+96] = bR3.y;                  \
    Bs[nb_][s0*4+2][r0+96] = bR3.z; Bs[nb_][s0*4+3][r0+96] = bR3.w;

// ---------- kernel A: round-3 GEMM (64x128, 4x8 micro) + butterfly top-4 epilogue ----------
// grid (LQ/64, NBLK, NLVL), block 256 = 16x16. (256,1): proven ~236 VGPR, no spill.
// Row r's 16 threads (fixed ty, tx=0..15) are contiguous lanes of ONE wave.
__global__ __launch_bounds__(256, 1) void gemm_topk_z(
    const float* __restrict__ Qm, const float* __restrict__ Vm,
    float* __restrict__ cv, int* __restrict__ ci)
{
  const int tid  = threadIdx.x;
  const int mgrp = blockIdx.x;
  const int nb2  = blockIdx.y;
  const int l    = blockIdx.z;
  const int ty = tid >> 4, tx = tid & 15;
  const int r0 = tid >> 3, s0 = tid & 7;

  __shared__ __align__(16) float As[2][KB][BM + 4];   // 17.4 KB
  __shared__ __align__(16) float Bs[2][KB][BN + 4];   // 33.8 KB

  const float* Aslab = Qm + (size_t)mgrp * BM * DM;
  const float* Bslab = Vm + ((size_t)l * LVLN + (size_t)nb2 * BN) * DM;

  float4 c0l = {0,0,0,0}, c0h = {0,0,0,0};
  float4 c1l = {0,0,0,0}, c1h = {0,0,0,0};
  float4 c2l = {0,0,0,0}, c2h = {0,0,0,0};
  float4 c3l = {0,0,0,0}, c3h = {0,0,0,0};

  float4 aR0, aR1, bR0, bR1, bR2, bR3;

  GLOAD(0)
  LSTORE(0)

#pragma unroll 1
  for (int kc = 0; kc < DM / KB; ++kc) {
    __syncthreads();
    if (kc < DM / KB - 1) {
      GLOAD((kc + 1) * KB)
    }
    const int buf = kc & 1;
#pragma unroll
    for (int k = 0; k < KB; ++k) {
      const float4 av = *(const float4*)&As[buf][k][ty * 4];
      const float4 b0 = *(const float4*)&Bs[buf][k][tx * 4];
      const float4 b1 = *(const float4*)&Bs[buf][k][64 + tx * 4];
      FMA4(c0l, av.x, b0) FMA4(c0h, av.x, b1)
      FMA4(c1l, av.y, b0) FMA4(c1h, av.y, b1)
      FMA4(c2l, av.z, b0) FMA4(c2h, av.z, b1)
      FMA4(c3l, av.w, b0) FMA4(c3h, av.w, b1)
    }
    if (kc < DM / KB - 1) {
      LSTORE((kc & 1) ^ 1)
    }
  }

  // ---- epilogue: per-thread strict top-4 per row (idx ascending) ----
  const float4 NEGI = {-3.4e38f, -3.4e38f, -3.4e38f, -3.4e38f};
  const int4   MAXI = {0x7fffffff, 0x7fffffff, 0x7fffffff, 0x7fffffff};
  const int bl = nb2 * BN + tx * 4;       // level-local col of low quad
  float4 tv0 = NEGI, tv1 = NEGI, tv2 = NEGI, tv3 = NEGI;
  int4   ti0 = MAXI, ti1 = MAXI, ti2 = MAXI, ti3 = MAXI;

  ins4(c0l.x, bl + 0, tv0, ti0);  ins4(c0l.y, bl + 1, tv0, ti0);
  ins4(c0l.z, bl + 2, tv0, ti0);  ins4(c0l.w, bl + 3, tv0, ti0);
  ins4(c0h.x, bl + 64, tv0, ti0); ins4(c0h.y, bl + 65, tv0, ti0);
  ins4(c0h.z, bl + 66, tv0, ti0); ins4(c0h.w, bl + 67, tv0, ti0);

  ins4(c1l.x, bl + 0, tv1, ti1);  ins4(c1l.y, bl + 1, tv1, ti1);
  ins4(c1l.z, bl + 2, tv1, ti1);  ins4(c1l.w, bl + 3, tv1, ti1);
  ins4(c1h.x, bl + 64, tv1, ti1); ins4(c1h.y, bl + 65, tv1, ti1);
  ins4(c1h.z, bl + 66, tv1, ti1); ins4(c1h.w, bl + 67, tv1, ti1);

  ins4(c2l.x, bl + 0, tv2, ti2);  ins4(c2l.y, bl + 1, tv2, ti2);
  ins4(c2l.z, bl + 2, tv2, ti2);  ins4(c2l.w, bl + 3, tv2, ti2);
  ins4(c2h.x, bl + 64, tv2, ti2); ins4(c2h.y, bl + 65, tv2, ti2);
  ins4(c2h.z, bl + 66, tv2, ti2); ins4(c2h.w, bl + 67, tv2, ti2);

  ins4(c3l.x, bl + 0, tv3, ti3);  ins4(c3l.y, bl + 1, tv3, ti3);
  ins4(c3l.z, bl + 2, tv3, ti3);  ins4(c3l.w, bl + 3, tv3, ti3);
  ins4(c3h.x, bl + 64, tv3, ti3); ins4(c3h.y, bl + 65, tv3, ti3);
  ins4(c3h.z, bl + 66, tv3, ti3); ins4(c3h.w, bl + 67, tv3, ti3);

  // ---- 16-lane butterfly merge (in-wave, no LDS, no barriers) ----
  // lanes with the same ty hold disjoint column sets -> no duplicates.
#define BMERGE(tv, ti, d)                                                    \
  {                                                                          \
    const float mx = __shfl_xor(tv.x, d), my = __shfl_xor(tv.y, d),          \
                mz = __shfl_xor(tv.z, d), mw = __shfl_xor(tv.w, d);          \
    const int   jx = __shfl_xor(ti.x, d), jy = __shfl_xor(ti.y, d),          \
                jz = __shfl_xor(ti.z, d), jw = __shfl_xor(ti.w, d);          \
    ins4_tb(mx, jx, tv, ti);                                                 \
    ins4_tb(my, jy, tv, ti);                                                 \
    ins4_tb(mz, jz, tv, ti);                                                 \
    ins4_tb(mw, jw, tv, ti);                                                 \
  }

#pragma unroll
  for (int d = 1; d < 16; d <<= 1) {
    BMERGE(tv0, ti0, d)
    BMERGE(tv1, ti1, d)
    BMERGE(tv2, ti2, d)
    BMERGE(tv3, ti3, d)
  }
#undef BMERGE

  if (tx == 0) {
    const int q0 = mgrp * BM + ty * 4;
    size_t o = (((size_t)l * LQ + q0) * NBLK + nb2) * 4;
    *(float4*)(cv + o) = tv0;  *(int4*)(ci + o) = ti0;
    o += (size_t)NBLK * 4;
    *(float4*)(cv + o) = tv1;  *(int4*)(ci + o) = ti1;
    o += (size_t)NBLK * 4;
    *(float4*)(cv + o) = tv2;  *(int4*)(ci + o) = ti2;
    o += (size_t)NBLK * 4;
    *(float4*)(cv + o) = tv3;  *(int4*)(ci + o) = ti3;
  }
}

// ---------- kernel B: merge 32 col-blocks -> final top-4, emit tix + sloc ----------
// one thread per (q, level); cv/ci are [NLVL][LQ][NBLK][4]
__global__ __launch_bounds__(256) void merge_topk(
    const float* __restrict__ cv, const int* __restrict__ ci,
    int* __restrict__ tix, float* __restrict__ sloc)
{
  const int g = blockIdx.x * 256 + threadIdx.x;
  if (g >= LQ * NLVL) return;
  const int q = g >> 2, l = g & 3;

  const float4 NEGI = {-3.4e38f, -3.4e38f, -3.4e38f, -3.4e38f};
  const int4   MAXI = {0x7fffffff, 0x7fffffff, 0x7fffffff, 0x7fffffff};
  float4 bv = NEGI;
  int4   bi = MAXI;

  const float* cvp = cv + (((size_t)l * LQ + q) * NBLK) * 4;
  const int*   cip = ci + (((size_t)l * LQ + q) * NBLK) * 4;
#pragma unroll 1
  for (int nb = 0; nb < NBLK; ++nb) {
    const float4 v = *(const float4*)(cvp + nb * 4);
    const int4   x = *(const int4*)(cip + nb * 4);
    ins4_tb(v.x, x.x, bv, bi);
    ins4_tb(v.y, x.y, bv, bi);
    ins4_tb(v.z, x.z, bv, bi);
    ins4_tb(v.w, x.w, bv, bi);
  }

  int bia[4] = {bi.x, bi.y, bi.z, bi.w};
  float* sl = sloc + (size_t)g * 72;   // 36 points * 2
#pragma unroll
  for (int p = 0; p < 4; ++p) {
    const int li = bia[p];             // level-local index [0,4096)
    tix[g * 4 + p] = li;
#pragma unroll
    for (int n9 = 0; n9 < 9; ++n9) {
      const int dy = n9 / 3 - 1, dx = n9 % 3 - 1;
      int r = li + dy * 64 + dx;
      r = r < 0 ? 0 : (r > CLIPMX ? CLIPMX : r);
      sl[(n9 * 4 + p) * 2 + 0] = (float)(r >> 6) * 0.015625f;
      sl[(n9 * 4 + p) * 2 + 1] = (float)(r & 63) * 0.015625f;
    }
  }
}

// ---------- kernel C: gather + accumulate pre-projection output ----------
__global__ void samp_acc(const float* __restrict__ V, const int* __restrict__ tix,
                         float* __restrict__ pre)
{
  const int q = blockIdx.x, d = threadIdx.x;
  const int nei[9] = {-65, -64, -63, -1, 0, 1, 63, 64, 65};
  float acc = 0.f;
#pragma unroll 1
  for (int l = 0; l < NLVL; ++l) {
    const float* Vb = V + (size_t)l * LVLN * DM;
    for (int p = 0; p < 4; ++p) {
      const int p0 = tix[(q * NLVL + l) * 4 + p];
      const int xw = p0 >> 6, yh = p0 & 63;
      if (p0 >= 65 && p0 <= 3904 && yh >= 1 && yh <= 62) {
        // fast path: 4x4 window, weights [1,2,2,1] x [1,2,2,1]
#pragma unroll
        for (int a = 0; a < 4; ++a) {
          const int y = yh - 2 + a;
          if (y < 0) continue;
          const float wa = (a == 1 || a == 2) ? 2.f : 1.f;
#pragma unroll
          for (int bb = 0; bb < 4; ++bb) {
            const int x = xw - 2 + bb;
            if (x < 0) continue;
            const float wb = (bb == 1 || bb == 2) ? 2.f : 1.f;
            acc = fmaf(wa * wb, Vb[(size_t)(y * 64 + x) * DM + d], acc);
          }
        }
      } else {
        // exact per-neighbor path with clip + border masks
#pragma unroll
        for (int n9 = 0; n9 < 9; ++n9) {
          int r = p0 + nei[n9];
          r = r < 0 ? 0 : (r > CLIPMX ? CLIPMX : r);
          const int x = r >> 6, y = r & 63;
          const int b0 = y * 64 + x;
          float s = Vb[(size_t)b0 * DM + d];
          if (x > 0) s += Vb[(size_t)(b0 - 1) * DM + d];
          if (y > 0) {
            s += Vb[(size_t)(b0 - 64) * DM + d];
            if (x > 0) s += Vb[(size_t)(b0 - 65) * DM + d];
          }
          acc += s;
        }
      }
    }
  }
  pre[(size_t)q * DM + d] = acc * (0.25f / 144.f);
}

// ---------- kernel D0: transpose out_w (256x256) ----------
__global__ void transp_w(const float* __restrict__ W, float* __restrict__ Wt)
{
  __shared__ float t[32][33];
  const int bx = blockIdx.x * 32, by = blockIdx.y * 32;
  t[threadIdx.y][threadIdx.x] = W[(size_t)(by + threadIdx.y) * DM + bx + threadIdx.x];
  __syncthreads();
  Wt[(size_t)(bx + threadIdx.y) * DM + by + threadIdx.x] = t[threadIdx.x][threadIdx.y];
}

// ---------- kernel D: out = pre @ W^T + b ----------
__global__ __launch_bounds__(256) void proj_out(
    const float* __restrict__ pre, const float* __restrict__ Wt,
    const float* __restrict__ bias, float* __restrict__ outp)
{
  const int q0 = blockIdx.x * QB;
  const int e = threadIdx.x;
  float acc[QB];
#pragma unroll
  for (int i = 0; i < QB; ++i) acc[i] = 0.f;
#pragma unroll 4
  for (int d = 0; d < DM; ++d) {
    const float w = Wt[(size_t)d * DM + e];
#pragma unroll
    for (int qq = 0; qq < QB; ++qq)
      acc[qq] = fmaf(pre[(size_t)(q0 + qq) * DM + d], w, acc[qq]);
  }
  const float be = bias[e];
#pragma unroll
  for (int qq = 0; qq < QB; ++qq)
    outp[(size_t)(q0 + qq) * DM + e] = acc[qq] + be;
}

extern "C" void kernel_launch(void* const* d_in, const int* in_sizes, int n_in,
                              void* d_out, int out_size, void* d_ws, size_t ws_size,
                              hipStream_t stream)
{
  const float* Q    = (const float*)d_in[0];   // [2048][256]
  const float* V    = (const float*)d_in[2];   // [16384][256]
  const float* W    = (const float*)d_in[5];   // [256][256]
  const float* bias = (const float*)d_in[6];   // [256]

  float* outp = (float*)d_out;                 // [2048][256]
  float* sloc = outp + (size_t)LQ * DM;        // [2048][4][36][2]

  char* ws = (char*)d_ws;
  const size_t MB = 1 << 20;
  // cand buffers: [NLVL][LQ][NBLK][4] = 1M entries each
  float* cv  = (float*)(ws);                   // 4 MB
  int*   ci  = (int*)  (ws + 4 * MB);          // 4 MB
  int*   tix = (int*)  (ws + 8 * MB);          // 128 KB
  float* pre = (float*)(ws + 8 * MB + 256 * 1024);    // 2 MB
  float* Wt  = (float*)(ws + 10 * MB + 256 * 1024);   // 256 KB

  gemm_topk_z<<<dim3(LQ / BM, NBLK, NLVL), 256, 0, stream>>>(Q, V, cv, ci);
  merge_topk<<<dim3((LQ * NLVL + 255) / 256), 256, 0, stream>>>(cv, ci, tix, sloc);
  samp_acc<<<dim3(LQ), 256, 0, stream>>>(V, tix, pre);
  transp_w<<<dim3(8, 8), dim3(32, 32), 0, stream>>>(W, Wt);
  proj_out<<<dim3(LQ / QB), 256, 0, stream>>>(pre, Wt, bias, outp);
}

// Round 11
// 394.962 us; speedup vs baseline: 6.1224x; 1.8639x over previous
//
#include <hip/hip_runtime.h>
#include <cstdint>
#include <cstddef>

#define LQ     2048
#define DM     256
#define NKEY   16384
#define NLVL   4
#define LVLN   4096
#define BM     64
#define BN     128
#define KB     16
#define MGRPS  (LQ / BM)
#define CLIPMX 3969
#define QB     8

// ---------- branchless sorted-insert into top-4, register-only ----------
// strict: later-inserted equal values lose (valid when idx inserted ascending)
__device__ __forceinline__ void ins4(float v, int ix, float4& tv, int4& ti) {
  bool c0 = v > tv.x, c1 = v > tv.y, c2 = v > tv.z, c3 = v > tv.w;
  tv.w = c2 ? tv.z : (c3 ? v : tv.w);
  ti.w = c2 ? ti.z : (c3 ? ix : ti.w);
  tv.z = c1 ? tv.y : (c2 ? v : tv.z);
  ti.z = c1 ? ti.y : (c2 ? ix : ti.z);
  tv.y = c0 ? tv.x : (c1 ? v : tv.y);
  ti.y = c0 ? ti.x : (c1 ? ix : ti.y);
  tv.x = c0 ? v : tv.x;
  ti.x = c0 ? ix : ti.x;
}

// tie-break: equal value -> smaller index wins (numpy/jax top_k semantics)
__device__ __forceinline__ void ins4_tb(float v, int ix, float4& tv, int4& ti) {
  bool c0 = (v > tv.x) || (v == tv.x && ix < ti.x);
  bool c1 = (v > tv.y) || (v == tv.y && ix < ti.y);
  bool c2 = (v > tv.z) || (v == tv.z && ix < ti.z);
  bool c3 = (v > tv.w) || (v == tv.w && ix < ti.w);
  tv.w = c2 ? tv.z : (c3 ? v : tv.w);
  ti.w = c2 ? ti.z : (c3 ? ix : ti.w);
  tv.z = c1 ? tv.y : (c2 ? v : tv.z);
  ti.z = c1 ? ti.y : (c2 ? ix : ti.z);
  tv.y = c0 ? tv.x : (c1 ? v : tv.y);
  ti.y = c0 ? ti.x : (c1 ? ix : ti.y);
  tv.x = c0 ? v : tv.x;
  ti.x = c0 ? ix : ti.x;
}

#define FMA4(accv, s, bv)                  \
  accv.x = fmaf(s, bv.x, accv.x);          \
  accv.y = fmaf(s, bv.y, accv.y);          \
  accv.z = fmaf(s, bv.z, accv.z);          \
  accv.w = fmaf(s, bv.w, accv.w);

// KB=16 staging: A 64x16 = 1 float4/thread; B 128x16 = 2 float4/thread.
// r4 = tid>>2 (0..63), s4 = tid&3 (slot of 4 cols)
#define GLOAD16(ko)                                                          \
    aR0 = *(const float4*)(Aslab + (size_t)(r4)      * DM + (ko) + s4 * 4);  \
    bR0 = *(const float4*)(Bslab + (size_t)(r4)      * DM + (ko) + s4 * 4);  \
    bR1 = *(const float4*)(Bslab + (size_t)(r4 + 64) * DM + (ko) + s4 * 4);

#define LSTORE16(nb_)                                                                \
    As[nb_][s4*4+0][r4]    = aR0.x; As[nb_][s4*4+1][r4]    = aR0.y;                  \
    As[nb_][s4*4+2][r4]    = aR0.z; As[nb_][s4*4+3][r4]    = aR0.w;                  \
    Bs[nb_][s4*4+0][r4]    = bR0.x; Bs[nb_][s4*4+1][r4]    = bR0.y;                  \
    Bs[nb_][s4*4+2][r4]    = bR0.z; Bs[nb_][s4*4+3][r4]    = bR0.w;                  \
    Bs[nb_][s4*4+0][r4+64] = bR1.x; Bs[nb_][s4*4+1][r4+64] = bR1.y;                  \
    Bs[nb_][s4*4+2][r4+64] = bR1.z; Bs[nb_][s4*4+3][r4+64] = bR1.w;

// ---------- kernel A: fp32 GEMM, KB=16, 4x8 micro, (256,2) for co-residency ----------
// grid (MGRPS, LVLN/BN) per level. C is [2048][4096] level-local.
__global__ __launch_bounds__(256, 2) void gemm_qk16(
    const float* __restrict__ Qm, const float* __restrict__ Kb,
    float* __restrict__ C)
{
  const int tid  = threadIdx.x;
  const int mgrp = blockIdx.x;
  const int nb2  = blockIdx.y;
  const int ty = tid >> 4, tx = tid & 15;
  const int r4 = tid >> 2, s4 = tid & 3;

  __shared__ __align__(16) float As[2][KB][BM + 4];   // 2*16*68*4  =  8.7 KB
  __shared__ __align__(16) float Bs[2][KB][BN + 4];   // 2*16*132*4 = 16.9 KB

  const float* Aslab = Qm + (size_t)mgrp * BM * DM;
  const float* Bslab = Kb + (size_t)nb2 * BN * DM;

  float4 c0l = {0,0,0,0}, c0h = {0,0,0,0};
  float4 c1l = {0,0,0,0}, c1h = {0,0,0,0};
  float4 c2l = {0,0,0,0}, c2h = {0,0,0,0};
  float4 c3l = {0,0,0,0}, c3h = {0,0,0,0};

  float4 aR0, bR0, bR1;

  GLOAD16(0)
  LSTORE16(0)

#pragma unroll 1
  for (int kc = 0; kc < DM / KB; ++kc) {
    __syncthreads();
    if (kc < DM / KB - 1) {
      GLOAD16((kc + 1) * KB)
    }
    const int buf = kc & 1;
#pragma unroll
    for (int k = 0; k < KB; ++k) {
      const float4 av = *(const float4*)&As[buf][k][ty * 4];
      const float4 b0 = *(const float4*)&Bs[buf][k][tx * 4];
      const float4 b1 = *(const float4*)&Bs[buf][k][64 + tx * 4];
      FMA4(c0l, av.x, b0) FMA4(c0h, av.x, b1)
      FMA4(c1l, av.y, b0) FMA4(c1h, av.y, b1)
      FMA4(c2l, av.z, b0) FMA4(c2h, av.z, b1)
      FMA4(c3l, av.w, b0) FMA4(c3h, av.w, b1)
    }
    if (kc < DM / KB - 1) {
      LSTORE16((kc & 1) ^ 1)
    }
  }

  float* Cp = C + (size_t)(mgrp * BM + ty * 4) * LVLN + nb2 * BN + tx * 4;
  *(float4*)(Cp + 0 * LVLN)      = c0l;  *(float4*)(Cp + 0 * LVLN + 64) = c0h;
  *(float4*)(Cp + 1 * LVLN)      = c1l;  *(float4*)(Cp + 1 * LVLN + 64) = c1h;
  *(float4*)(Cp + 2 * LVLN)      = c2l;  *(float4*)(Cp + 2 * LVLN + 64) = c2h;
  *(float4*)(Cp + 3 * LVLN)      = c3l;  *(float4*)(Cp + 3 * LVLN + 64) = c3h;
}

// ---------- kernel B: per-(q,level) top-4 + emit tix/sloc (round-3-proven) ----------
// one wave per q-row; grid LQ/4 x 256 threads, per level.
__global__ __launch_bounds__(256) void topk_loc(
    const float* __restrict__ C, const int lvl,
    int* __restrict__ tix, float* __restrict__ sloc)
{
  const int wid  = threadIdx.x >> 6;
  const int lane = threadIdx.x & 63;
  const int q = blockIdx.x * 4 + wid;
  const float* row = C + (size_t)q * LVLN;

  const float4 NEGI = {-3.4e38f, -3.4e38f, -3.4e38f, -3.4e38f};
  const int4   MAXI = {0x7fffffff, 0x7fffffff, 0x7fffffff, 0x7fffffff};
  float4 tv = NEGI;
  int4   ti = MAXI;

#pragma unroll
  for (int it = 0; it < 16; ++it) {
    const int col = it * 256 + lane * 4;
    const float4 v = *(const float4*)(row + col);
    ins4(v.x, col + 0, tv, ti);
    ins4(v.y, col + 1, tv, ti);
    ins4(v.z, col + 2, tv, ti);
    ins4(v.w, col + 3, tv, ti);
  }
#pragma unroll
  for (int d = 1; d < 64; d <<= 1) {
    const float ovx = __shfl_xor(tv.x, d), ovy = __shfl_xor(tv.y, d),
                ovz = __shfl_xor(tv.z, d), ovw = __shfl_xor(tv.w, d);
    const int   oix = __shfl_xor(ti.x, d), oiy = __shfl_xor(ti.y, d),
                oiz = __shfl_xor(ti.z, d), oiw = __shfl_xor(ti.w, d);
    ins4_tb(ovx, oix, tv, ti);
    ins4_tb(ovy, oiy, tv, ti);
    ins4_tb(ovz, oiz, tv, ti);
    ins4_tb(ovw, oiw, tv, ti);
  }

  const int g = q * NLVL + lvl;
  if (lane < 4) {
    const int li = lane == 0 ? ti.x : (lane == 1 ? ti.y : (lane == 2 ? ti.z : ti.w));
    tix[g * 4 + lane] = li;
  }
  if (lane < 36) {
    const int p  = lane & 3, n9 = lane >> 2;
    const int li = p == 0 ? ti.x : (p == 1 ? ti.y : (p == 2 ? ti.z : ti.w));
    const int dy = n9 / 3 - 1, dx = n9 % 3 - 1;
    int r = li + dy * 64 + dx;
    r = r < 0 ? 0 : (r > CLIPMX ? CLIPMX : r);
    sloc[(size_t)g * 72 + lane * 2 + 0] = (float)(r >> 6) * 0.015625f;
    sloc[(size_t)g * 72 + lane * 2 + 1] = (float)(r & 63) * 0.015625f;
  }
}

// ---------- kernel C: gather + accumulate pre-projection output ----------
__global__ void samp_acc(const float* __restrict__ V, const int* __restrict__ tix,
                         float* __restrict__ pre)
{
  const int q = blockIdx.x, d = threadIdx.x;
  const int nei[9] = {-65, -64, -63, -1, 0, 1, 63, 64, 65};
  float acc = 0.f;
#pragma unroll 1
  for (int l = 0; l < NLVL; ++l) {
    const float* Vb = V + (size_t)l * LVLN * DM;
    for (int p = 0; p < 4; ++p) {
      const int p0 = tix[(q * NLVL + l) * 4 + p];
      const int xw = p0 >> 6, yh = p0 & 63;
      if (p0 >= 65 && p0 <= 3904 && yh >= 1 && yh <= 62) {
        // fast path: 4x4 window, weights [1,2,2,1] x [1,2,2,1]
#pragma unroll
        for (int a = 0; a < 4; ++a) {
          const int y = yh - 2 + a;
          if (y < 0) continue;
          const float wa = (a == 1 || a == 2) ? 2.f : 1.f;
#pragma unroll
          for (int bb = 0; bb < 4; ++bb) {
            const int x = xw - 2 + bb;
            if (x < 0) continue;
            const float wb = (bb == 1 || bb == 2) ? 2.f : 1.f;
            acc = fmaf(wa * wb, Vb[(size_t)(y * 64 + x) * DM + d], acc);
          }
        }
      } else {
        // exact per-neighbor path with clip + border masks
#pragma unroll
        for (int n9 = 0; n9 < 9; ++n9) {
          int r = p0 + nei[n9];
          r = r < 0 ? 0 : (r > CLIPMX ? CLIPMX : r);
          const int x = r >> 6, y = r & 63;
          const int b0 = y * 64 + x;
          float s = Vb[(size_t)b0 * DM + d];
          if (x > 0) s += Vb[(size_t)(b0 - 1) * DM + d];
          if (y > 0) {
            s += Vb[(size_t)(b0 - 64) * DM + d];
            if (x > 0) s += Vb[(size_t)(b0 - 65) * DM + d];
          }
          acc += s;
        }
      }
    }
  }
  pre[(size_t)q * DM + d] = acc * (0.25f / 144.f);
}

// ---------- kernel D0: transpose out_w (256x256) ----------
__global__ void transp_w(const float* __restrict__ W, float* __restrict__ Wt)
{
  __shared__ float t[32][33];
  const int bx = blockIdx.x * 32, by = blockIdx.y * 32;
  t[threadIdx.y][threadIdx.x] = W[(size_t)(by + threadIdx.y) * DM + bx + threadIdx.x];
  __syncthreads();
  Wt[(size_t)(bx + threadIdx.y) * DM + by + threadIdx.x] = t[threadIdx.x][threadIdx.y];
}

// ---------- kernel D: out = pre @ W^T + b ----------
__global__ __launch_bounds__(256) void proj_out(
    const float* __restrict__ pre, const float* __restrict__ Wt,
    const float* __restrict__ bias, float* __restrict__ outp)
{
  const int q0 = blockIdx.x * QB;
  const int e = threadIdx.x;
  float acc[QB];
#pragma unroll
  for (int i = 0; i < QB; ++i) acc[i] = 0.f;
#pragma unroll 4
  for (int d = 0; d < DM; ++d) {
    const float w = Wt[(size_t)d * DM + e];
#pragma unroll
    for (int qq = 0; qq < QB; ++qq)
      acc[qq] = fmaf(pre[(size_t)(q0 + qq) * DM + d], w, acc[qq]);
  }
  const float be = bias[e];
#pragma unroll
  for (int qq = 0; qq < QB; ++qq)
    outp[(size_t)(q0 + qq) * DM + e] = acc[qq] + be;
}

extern "C" void kernel_launch(void* const* d_in, const int* in_sizes, int n_in,
                              void* d_out, int out_size, void* d_ws, size_t ws_size,
                              hipStream_t stream)
{
  const float* Q    = (const float*)d_in[0];   // [2048][256]
  const float* V    = (const float*)d_in[2];   // [16384][256]
  const float* W    = (const float*)d_in[5];   // [256][256]
  const float* bias = (const float*)d_in[6];   // [256]

  float* outp = (float*)d_out;                 // [2048][256]
  float* sloc = outp + (size_t)LQ * DM;        // [2048][4][36][2]

  char* ws = (char*)d_ws;
  const size_t CORR_B = (size_t)LQ * LVLN * 4; // 33.5 MB (proven available, round 3)

  float* corr = (float*)ws;
  int*   tix  = (int*)(ws + CORR_B);
  float* pre  = (float*)(ws + CORR_B + 131072);
  float* Wt   = (float*)(ws + CORR_B + 131072 + 2097152);

  for (int l = 0; l < NLVL; ++l) {
    gemm_qk16<<<dim3(MGRPS, LVLN / BN), 256, 0, stream>>>(
        Q, V + (size_t)l * LVLN * DM, corr);
    topk_loc<<<dim3(LQ / 4), 256, 0, stream>>>(corr, l, tix, sloc);
  }
  samp_acc<<<dim3(LQ), 256, 0, stream>>>(V, tix, pre);
  transp_w<<<dim3(8, 8), dim3(32, 32), 0, stream>>>(W, Wt);
  proj_out<<<dim3(LQ / QB), 256, 0, stream>>>(pre, Wt, bias, outp);
}

// Round 13
// 362.701 us; speedup vs baseline: 6.6669x; 1.0889x over previous
//
#include <hip/hip_runtime.h>
#include <cstdint>
#include <cstddef>

#define LQ     2048
#define DM     256
#define NKEY   16384
#define NLVL   4
#define LVLN   4096
#define BM     64
#define BN     128
#define KB     16
#define MGRPS  (LQ / BM)
#define CLIPMX 3969
#define QB     8

// ---------- branchless sorted-insert into top-4, register-only ----------
// strict: later-inserted equal values lose (valid when idx inserted ascending)
__device__ __forceinline__ void ins4(float v, int ix, float4& tv, int4& ti) {
  bool c0 = v > tv.x, c1 = v > tv.y, c2 = v > tv.z, c3 = v > tv.w;
  tv.w = c2 ? tv.z : (c3 ? v : tv.w);
  ti.w = c2 ? ti.z : (c3 ? ix : ti.w);
  tv.z = c1 ? tv.y : (c2 ? v : tv.z);
  ti.z = c1 ? ti.y : (c2 ? ix : ti.z);
  tv.y = c0 ? tv.x : (c1 ? v : tv.y);
  ti.y = c0 ? ti.x : (c1 ? ix : ti.y);
  tv.x = c0 ? v : tv.x;
  ti.x = c0 ? ix : ti.x;
}

// tie-break: equal value -> smaller index wins (numpy/jax top_k semantics)
__device__ __forceinline__ void ins4_tb(float v, int ix, float4& tv, int4& ti) {
  bool c0 = (v > tv.x) || (v == tv.x && ix < ti.x);
  bool c1 = (v > tv.y) || (v == tv.y && ix < ti.y);
  bool c2 = (v > tv.z) || (v == tv.z && ix < ti.z);
  bool c3 = (v > tv.w) || (v == tv.w && ix < ti.w);
  tv.w = c2 ? tv.z : (c3 ? v : tv.w);
  ti.w = c2 ? ti.z : (c3 ? ix : ti.w);
  tv.z = c1 ? tv.y : (c2 ? v : tv.z);
  ti.z = c1 ? ti.y : (c2 ? ix : ti.z);
  tv.y = c0 ? tv.x : (c1 ? v : tv.y);
  ti.y = c0 ? ti.x : (c1 ? ix : ti.y);
  tv.x = c0 ? v : tv.x;
  ti.x = c0 ? ix : ti.x;
}

// vector helpers (functions, not macros — macro-hygiene lesson from round 12)
__device__ __forceinline__ void fma4v(float4& acc, float s, const float4& v) {
  acc.x = fmaf(s, v.x, acc.x);
  acc.y = fmaf(s, v.y, acc.y);
  acc.z = fmaf(s, v.z, acc.z);
  acc.w = fmaf(s, v.w, acc.w);
}
__device__ __forceinline__ void add4(float4& acc, const float4& v) {
  acc.x += v.x; acc.y += v.y; acc.z += v.z; acc.w += v.w;
}

#define FMA4(accv, s, bv)                  \
  accv.x = fmaf(s, bv.x, accv.x);          \
  accv.y = fmaf(s, bv.y, accv.y);          \
  accv.z = fmaf(s, bv.z, accv.z);          \
  accv.w = fmaf(s, bv.w, accv.w);

// KB=16 staging: A 64x16 = 1 float4/thread; B 128x16 = 2 float4/thread.
#define GLOAD16(ko)                                                          \
    aR0 = *(const float4*)(Aslab + (size_t)(r4)      * DM + (ko) + s4 * 4);  \
    bR0 = *(const float4*)(Bslab + (size_t)(r4)      * DM + (ko) + s4 * 4);  \
    bR1 = *(const float4*)(Bslab + (size_t)(r4 + 64) * DM + (ko) + s4 * 4);

#define LSTORE16(nb_)                                                                \
    As[nb_][s4*4+0][r4]    = aR0.x; As[nb_][s4*4+1][r4]    = aR0.y;                  \
    As[nb_][s4*4+2][r4]    = aR0.z; As[nb_][s4*4+3][r4]    = aR0.w;                  \
    Bs[nb_][s4*4+0][r4]    = bR0.x; Bs[nb_][s4*4+1][r4]    = bR0.y;                  \
    Bs[nb_][s4*4+2][r4]    = bR0.z; Bs[nb_][s4*4+3][r4]    = bR0.w;                  \
    Bs[nb_][s4*4+0][r4+64] = bR1.x; Bs[nb_][s4*4+1][r4+64] = bR1.y;                  \
    Bs[nb_][s4*4+2][r4+64] = bR1.z; Bs[nb_][s4*4+3][r4+64] = bR1.w;

// ---------- kernel A: fp32 GEMM, KB=16, 4x8 micro, (256,2) for co-residency ----------
__global__ __launch_bounds__(256, 2) void gemm_qk16(
    const float* __restrict__ Qm, const float* __restrict__ Kb,
    float* __restrict__ C)
{
  const int tid  = threadIdx.x;
  const int mgrp = blockIdx.x;
  const int nb2  = blockIdx.y;
  const int ty = tid >> 4, tx = tid & 15;
  const int r4 = tid >> 2, s4 = tid & 3;

  __shared__ __align__(16) float As[2][KB][BM + 4];   //  8.7 KB
  __shared__ __align__(16) float Bs[2][KB][BN + 4];   // 16.9 KB

  const float* Aslab = Qm + (size_t)mgrp * BM * DM;
  const float* Bslab = Kb + (size_t)nb2 * BN * DM;

  float4 c0l = {0,0,0,0}, c0h = {0,0,0,0};
  float4 c1l = {0,0,0,0}, c1h = {0,0,0,0};
  float4 c2l = {0,0,0,0}, c2h = {0,0,0,0};
  float4 c3l = {0,0,0,0}, c3h = {0,0,0,0};

  float4 aR0, bR0, bR1;

  GLOAD16(0)
  LSTORE16(0)

#pragma unroll 1
  for (int kc = 0; kc < DM / KB; ++kc) {
    __syncthreads();
    if (kc < DM / KB - 1) {
      GLOAD16((kc + 1) * KB)
    }
    const int buf = kc & 1;
#pragma unroll
    for (int k = 0; k < KB; ++k) {
      const float4 av = *(const float4*)&As[buf][k][ty * 4];
      const float4 b0 = *(const float4*)&Bs[buf][k][tx * 4];
      const float4 b1 = *(const float4*)&Bs[buf][k][64 + tx * 4];
      FMA4(c0l, av.x, b0) FMA4(c0h, av.x, b1)
      FMA4(c1l, av.y, b0) FMA4(c1h, av.y, b1)
      FMA4(c2l, av.z, b0) FMA4(c2h, av.z, b1)
      FMA4(c3l, av.w, b0) FMA4(c3h, av.w, b1)
    }
    if (kc < DM / KB - 1) {
      LSTORE16((kc & 1) ^ 1)
    }
  }

  float* Cp = C + (size_t)(mgrp * BM + ty * 4) * LVLN + nb2 * BN + tx * 4;
  *(float4*)(Cp + 0 * LVLN)      = c0l;  *(float4*)(Cp + 0 * LVLN + 64) = c0h;
  *(float4*)(Cp + 1 * LVLN)      = c1l;  *(float4*)(Cp + 1 * LVLN + 64) = c1h;
  *(float4*)(Cp + 2 * LVLN)      = c2l;  *(float4*)(Cp + 2 * LVLN + 64) = c2h;
  *(float4*)(Cp + 3 * LVLN)      = c3l;  *(float4*)(Cp + 3 * LVLN + 64) = c3h;
}

// ---------- kernel B: per-(q,level) top-4 + emit tix/sloc (proven) ----------
__global__ __launch_bounds__(256) void topk_loc(
    const float* __restrict__ C, const int lvl,
    int* __restrict__ tix, float* __restrict__ sloc)
{
  const int wid  = threadIdx.x >> 6;
  const int lane = threadIdx.x & 63;
  const int q = blockIdx.x * 4 + wid;
  const float* row = C + (size_t)q * LVLN;

  const float4 NEGI = {-3.4e38f, -3.4e38f, -3.4e38f, -3.4e38f};
  const int4   MAXI = {0x7fffffff, 0x7fffffff, 0x7fffffff, 0x7fffffff};
  float4 tv = NEGI;
  int4   ti = MAXI;

#pragma unroll
  for (int it = 0; it < 16; ++it) {
    const int col = it * 256 + lane * 4;
    const float4 v = *(const float4*)(row + col);
    ins4(v.x, col + 0, tv, ti);
    ins4(v.y, col + 1, tv, ti);
    ins4(v.z, col + 2, tv, ti);
    ins4(v.w, col + 3, tv, ti);
  }
#pragma unroll
  for (int d = 1; d < 64; d <<= 1) {
    const float ovx = __shfl_xor(tv.x, d), ovy = __shfl_xor(tv.y, d),
                ovz = __shfl_xor(tv.z, d), ovw = __shfl_xor(tv.w, d);
    const int   oix = __shfl_xor(ti.x, d), oiy = __shfl_xor(ti.y, d),
                oiz = __shfl_xor(ti.z, d), oiw = __shfl_xor(ti.w, d);
    ins4_tb(ovx, oix, tv, ti);
    ins4_tb(ovy, oiy, tv, ti);
    ins4_tb(ovz, oiz, tv, ti);
    ins4_tb(ovw, oiw, tv, ti);
  }

  const int g = q * NLVL + lvl;
  if (lane < 4) {
    const int li = lane == 0 ? ti.x : (lane == 1 ? ti.y : (lane == 2 ? ti.z : ti.w));
    tix[g * 4 + lane] = li;
  }
  if (lane < 36) {
    const int p  = lane & 3, n9 = lane >> 2;
    const int li = p == 0 ? ti.x : (p == 1 ? ti.y : (p == 2 ? ti.z : ti.w));
    const int dy = n9 / 3 - 1, dx = n9 % 3 - 1;
    int r = li + dy * 64 + dx;
    r = r < 0 ? 0 : (r > CLIPMX ? CLIPMX : r);
    sloc[(size_t)g * 72 + lane * 2 + 0] = (float)(r >> 6) * 0.015625f;
    sloc[(size_t)g * 72 + lane * 2 + 1] = (float)(r & 63) * 0.015625f;
  }
}

// ---------- kernel C: gather, parallel over (q, level, point), float4 channels ----------
// grid (LQ, NLVL), block 256 = 4 points x 64 lanes; lane covers channels lane*4..+3.
// writes per-level partial pre4[l][q][256] (unscaled).
__global__ __launch_bounds__(256) void samp_acc4(
    const float* __restrict__ V, const int* __restrict__ tix,
    float* __restrict__ pre4)
{
  const int q = blockIdx.x, l = blockIdx.y;
  const int p = threadIdx.x >> 6, lane = threadIdx.x & 63;
  const int c0 = lane * 4;
  const float* Vb = V + (size_t)l * LVLN * DM;

  const int p0 = tix[(q * NLVL + l) * 4 + p];
  const int xw = p0 >> 6, yh = p0 & 63;
  float4 acc = {0.f, 0.f, 0.f, 0.f};

  if (p0 >= 65 && p0 <= 3904 && yh >= 1 && yh <= 62) {
    // fast path: 4x4 window, weights [1,2,2,1] x [1,2,2,1]
#pragma unroll
    for (int a = 0; a < 4; ++a) {
      const int y = yh - 2 + a;
      if (y < 0) continue;
      const float wa = (a == 1 || a == 2) ? 2.f : 1.f;
#pragma unroll
      for (int bb = 0; bb < 4; ++bb) {
        const int x = xw - 2 + bb;
        if (x < 0) continue;
        const float wb = (bb == 1 || bb == 2) ? 2.f : 1.f;
        const float4 v = *(const float4*)(Vb + (size_t)(y * 64 + x) * DM + c0);
        fma4v(acc, wa * wb, v);
      }
    }
  } else {
    // exact per-neighbor path with clip + border masks
    const int nei[9] = {-65, -64, -63, -1, 0, 1, 63, 64, 65};
#pragma unroll
    for (int n9 = 0; n9 < 9; ++n9) {
      int r = p0 + nei[n9];
      r = r < 0 ? 0 : (r > CLIPMX ? CLIPMX : r);
      const int x = r >> 6, y = r & 63;
      const int b0 = y * 64 + x;
      float4 s = *(const float4*)(Vb + (size_t)b0 * DM + c0);
      if (x > 0) {
        const float4 v = *(const float4*)(Vb + (size_t)(b0 - 1) * DM + c0);
        add4(s, v);
      }
      if (y > 0) {
        const float4 v = *(const float4*)(Vb + (size_t)(b0 - 64) * DM + c0);
        add4(s, v);
        if (x > 0) {
          const float4 u = *(const float4*)(Vb + (size_t)(b0 - 65) * DM + c0);
          add4(s, u);
        }
      }
      add4(acc, s);
    }
  }

  __shared__ __align__(16) float4 red[4][64];
  red[p][lane] = acc;
  __syncthreads();
  if (p == 0) {
    const float4 a0 = red[0][lane], a1 = red[1][lane];
    const float4 a2 = red[2][lane], a3 = red[3][lane];
    float4 s;
    s.x = (a0.x + a1.x) + (a2.x + a3.x);
    s.y = (a0.y + a1.y) + (a2.y + a3.y);
    s.z = (a0.z + a1.z) + (a2.z + a3.z);
    s.w = (a0.w + a1.w) + (a2.w + a3.w);
    *(float4*)(pre4 + ((size_t)l * LQ + q) * DM + c0) = s;
  }
}

// ---------- kernel C2: pre = (sum over 4 levels of pre4) * (0.25/144) ----------
__global__ __launch_bounds__(256) void sum4(
    const float* __restrict__ pre4, float* __restrict__ pre)
{
  const size_t i = (size_t)blockIdx.x * 256 + threadIdx.x;   // float4 index
  const size_t n = (size_t)LQ * DM / 4;
  const float4 a = ((const float4*)pre4)[i];
  const float4 b = ((const float4*)pre4)[i + n];
  const float4 c = ((const float4*)pre4)[i + 2 * n];
  const float4 d = ((const float4*)pre4)[i + 3 * n];
  const float k = 0.25f / 144.f;
  float4 s;
  s.x = ((a.x + b.x) + (c.x + d.x)) * k;
  s.y = ((a.y + b.y) + (c.y + d.y)) * k;
  s.z = ((a.z + b.z) + (c.z + d.z)) * k;
  s.w = ((a.w + b.w) + (c.w + d.w)) * k;
  ((float4*)pre)[i] = s;
}

// ---------- kernel D0: transpose out_w (256x256) ----------
__global__ void transp_w(const float* __restrict__ W, float* __restrict__ Wt)
{
  __shared__ float t[32][33];
  const int bx = blockIdx.x * 32, by = blockIdx.y * 32;
  t[threadIdx.y][threadIdx.x] = W[(size_t)(by + threadIdx.y) * DM + bx + threadIdx.x];
  __syncthreads();
  Wt[(size_t)(bx + threadIdx.y) * DM + by + threadIdx.x] = t[threadIdx.x][threadIdx.y];
}

// ---------- kernel D: out = pre @ W^T + b ----------
__global__ __launch_bounds__(256) void proj_out(
    const float* __restrict__ pre, const float* __restrict__ Wt,
    const float* __restrict__ bias, float* __restrict__ outp)
{
  const int q0 = blockIdx.x * QB;
  const int e = threadIdx.x;
  float acc[QB];
#pragma unroll
  for (int i = 0; i < QB; ++i) acc[i] = 0.f;
#pragma unroll 4
  for (int d = 0; d < DM; ++d) {
    const float w = Wt[(size_t)d * DM + e];
#pragma unroll
    for (int qq = 0; qq < QB; ++qq)
      acc[qq] = fmaf(pre[(size_t)(q0 + qq) * DM + d], w, acc[qq]);
  }
  const float be = bias[e];
#pragma unroll
  for (int qq = 0; qq < QB; ++qq)
    outp[(size_t)(q0 + qq) * DM + e] = acc[qq] + be;
}

extern "C" void kernel_launch(void* const* d_in, const int* in_sizes, int n_in,
                              void* d_out, int out_size, void* d_ws, size_t ws_size,
                              hipStream_t stream)
{
  const float* Q    = (const float*)d_in[0];   // [2048][256]
  const float* V    = (const float*)d_in[2];   // [16384][256]
  const float* W    = (const float*)d_in[5];   // [256][256]
  const float* bias = (const float*)d_in[6];   // [256]

  float* outp = (float*)d_out;                 // [2048][256]
  float* sloc = outp + (size_t)LQ * DM;        // [2048][4][36][2]

  char* ws = (char*)d_ws;
  const size_t CORR_B = (size_t)LQ * LVLN * 4; // 33.5 MB (proven available)

  float* corr = (float*)ws;
  int*   tix  = (int*)(ws + CORR_B);
  float* pre  = (float*)(ws + CORR_B + 131072);
  float* Wt   = (float*)(ws + CORR_B + 131072 + 2097152);
  // pre4 [4][2048][256] = 8 MB aliases corr (dead after last topk_loc)
  float* pre4 = corr;

  for (int l = 0; l < NLVL; ++l) {
    gemm_qk16<<<dim3(MGRPS, LVLN / BN), 256, 0, stream>>>(
        Q, V + (size_t)l * LVLN * DM, corr);
    topk_loc<<<dim3(LQ / 4), 256, 0, stream>>>(corr, l, tix, sloc);
  }
  samp_acc4<<<dim3(LQ, NLVL), 256, 0, stream>>>(V, tix, pre4);
  sum4<<<dim3(LQ * DM / 1024), 256, 0, stream>>>(pre4, pre);
  transp_w<<<dim3(8, 8), dim3(32, 32), 0, stream>>>(W, Wt);
  proj_out<<<dim3(LQ / QB), 256, 0, stream>>>(pre, Wt, bias, outp);
}